// Round 7
// baseline (350.362 us; speedup 1.0000x reference)
//
#include <hip/hip_runtime.h>

// GraphSAGE: 2x SAGEConv(mean) + ReLU, then linear out.
// N=40000, E=640000, IN=H=128, OUT=64. ALL-f32 (round-2 numerics, proven).
// Round 7: GEMM compute remap — lane=node, wave=col-group. Per kk: 1 A float
// (distinct/lane, conflict-free) + 8 wave-uniform B float4s (LDS broadcast).
// Cuts LDS bytes/FMA ~8x (r5/r6 were LDS-BW-bound at ~44% VALU ceiling).
// Same k-ascending FMA order as r5 -> bit-identical output.
// agg/CSR unchanged from round 5. Workspace layout identical to round 2.

__global__ __launch_bounds__(256) void k_hist(const int* __restrict__ dst,
                                              int* __restrict__ cnt, int E) {
  int e = blockIdx.x * 256 + threadIdx.x;
  if (e < E) atomicAdd(&cnt[dst[e]], 1);
}

// Per-1024-block sums of cnt -> blockSums[b]
__global__ __launch_bounds__(1024) void k_bsum(const int* __restrict__ cnt,
                                               int* __restrict__ blockSums, int N) {
  __shared__ int ws[16];
  int i = blockIdx.x * 1024 + threadIdx.x;
  int v = (i < N) ? cnt[i] : 0;
#pragma unroll
  for (int d = 32; d > 0; d >>= 1) v += __shfl_xor(v, d, 64);
  if ((threadIdx.x & 63) == 0) ws[threadIdx.x >> 6] = v;
  __syncthreads();
  if (threadIdx.x == 0) {
    int s = 0;
#pragma unroll
    for (int w = 0; w < 16; ++w) s += ws[w];
    blockSums[blockIdx.x] = s;
  }
}

// Tiny serial scan of nb block sums (nb=40) -> blockOff; rowptr[N]=total.
__global__ __launch_bounds__(64) void k_bscan(const int* __restrict__ blockSums,
                                              int* __restrict__ blockOff,
                                              int* __restrict__ rowptr, int nb, int N) {
  if (threadIdx.x == 0) {
    int run = 0;
    for (int i = 0; i < nb; ++i) {
      blockOff[i] = run;
      run += blockSums[i];
    }
    rowptr[N] = run;
  }
}

// Per-block exclusive scan of cnt + blockOff -> rowptr, cursor.
__global__ __launch_bounds__(1024) void k_escan(const int* __restrict__ cnt,
                                                const int* __restrict__ blockOff,
                                                int* __restrict__ rowptr,
                                                int* __restrict__ cursor, int N) {
  __shared__ int warpSums[16];
  const int tid = threadIdx.x;
  const int lane = tid & 63, wid = tid >> 6;
  int i = blockIdx.x * 1024 + tid;
  int v = (i < N) ? cnt[i] : 0;
  int s = v;
#pragma unroll
  for (int d = 1; d < 64; d <<= 1) {
    int t = __shfl_up(s, d, 64);
    if (lane >= d) s += t;
  }
  if (lane == 63) warpSums[wid] = s;
  __syncthreads();
  if (tid < 16) {
    int w = warpSums[tid];
#pragma unroll
    for (int d = 1; d < 16; d <<= 1) {
      int t = __shfl_up(w, d, 16);
      if (tid >= d) w += t;
    }
    warpSums[tid] = w;
  }
  __syncthreads();
  int ex = blockOff[blockIdx.x] + (wid ? warpSums[wid - 1] : 0) + s - v;
  if (i < N) {
    rowptr[i] = ex;
    cursor[i] = ex;
  }
}

__global__ __launch_bounds__(256) void k_fill(const int* __restrict__ src,
                                              const int* __restrict__ dst,
                                              int* __restrict__ cursor,
                                              int* __restrict__ csr_src, int E) {
  int e = blockIdx.x * 256 + threadIdx.x;
  if (e < E) {
    int pos = atomicAdd(&cursor[dst[e]], 1);
    csr_src[pos] = src[e];
  }
}

// One wave per node: mean of f32 neighbor rows (128 feats).
// 64 lanes x float2 per row; 4 rows in flight per iteration.
__global__ __launch_bounds__(256) void k_agg(const float* __restrict__ feat,
                                             const int* __restrict__ rowptr,
                                             const int* __restrict__ csr_src,
                                             float* __restrict__ agg, int N) {
  int node = (blockIdx.x * 256 + threadIdx.x) >> 6;
  if (node >= N) return;
  const int lane = threadIdx.x & 63;
  const int beg = rowptr[node];
  const int deg = rowptr[node + 1] - beg;
  const int c = lane * 2;
  float2 a0 = {0.f, 0.f}, a1 = {0.f, 0.f}, a2 = {0.f, 0.f}, a3 = {0.f, 0.f};
  int j = 0;
  for (; j + 3 < deg; j += 4) {
    int s0 = csr_src[beg + j + 0];
    int s1 = csr_src[beg + j + 1];
    int s2 = csr_src[beg + j + 2];
    int s3 = csr_src[beg + j + 3];
    float2 v0 = *reinterpret_cast<const float2*>(feat + (size_t)s0 * 128 + c);
    float2 v1 = *reinterpret_cast<const float2*>(feat + (size_t)s1 * 128 + c);
    float2 v2 = *reinterpret_cast<const float2*>(feat + (size_t)s2 * 128 + c);
    float2 v3 = *reinterpret_cast<const float2*>(feat + (size_t)s3 * 128 + c);
    a0.x += v0.x; a0.y += v0.y;
    a1.x += v1.x; a1.y += v1.y;
    a2.x += v2.x; a2.y += v2.y;
    a3.x += v3.x; a3.y += v3.y;
  }
  for (; j < deg; ++j) {
    int s0 = csr_src[beg + j];
    float2 v0 = *reinterpret_cast<const float2*>(feat + (size_t)s0 * 128 + c);
    a0.x += v0.x; a0.y += v0.y;
  }
  float invd = 1.0f / fmaxf((float)deg, 1.0f);
  float2 o;
  o.x = (a0.x + a1.x + a2.x + a3.x) * invd;
  o.y = (a0.y + a1.y + a2.y + a3.y) * invd;
  *reinterpret_cast<float2*>(agg + (size_t)node * 128 + c) = o;
}

// Fused SAGE layer: out = relu([agg | root] @ [Wl; Wr] + b)
// 64 nodes x 128 cols per block; lane = node, wave = 32-col group, acc[32].
// Per kk: A[kk][lane] (1 float, conflict-free) + 8 wave-uniform B float4s
// (broadcast). K order identical to r5 (bit-identical output).
template <bool RELU>
__global__ __launch_bounds__(256) void k_sage_gemm(
    const float* __restrict__ agg, const float* __restrict__ root,
    const float* __restrict__ Wl, const float* __restrict__ Wr,
    const float* __restrict__ bias, float* __restrict__ out, int M) {
  __shared__ float A[32][65];    // [kk][node], stride 65: b32 reads conflict-free
  __shared__ float B[32][132];   // [kk][col]
  const int tid = threadIdx.x;
  const int lane = tid & 63;
  const int c0 = (tid >> 6) * 32;   // this wave's column base
  const int m0 = blockIdx.x * 64;
  float acc[32] = {};

  for (int k0 = 0; k0 < 256; k0 += 32) {
    __syncthreads();
    const bool isAgg = (k0 < 128);
    const float* Asrc = isAgg ? agg : root;
    const int kbase = isAgg ? k0 : (k0 - 128);
    // Stage A: 64 nodes x 32 k, transposed
#pragma unroll
    for (int j = 0; j < 2; ++j) {
      int idx = tid + j * 256;
      int r = idx >> 3;
      int c = (idx & 7) << 2;
      int n = m0 + r;
      if (n >= M) n = M - 1;
      float4 v = *reinterpret_cast<const float4*>(Asrc + (size_t)n * 128 + kbase + c);
      A[c + 0][r] = v.x; A[c + 1][r] = v.y; A[c + 2][r] = v.z; A[c + 3][r] = v.w;
    }
    // Stage B: 32 k x 128 cols
    const float* W = isAgg ? (Wl + (size_t)k0 * 128) : (Wr + (size_t)(k0 - 128) * 128);
#pragma unroll
    for (int j = 0; j < 4; ++j) {
      int idx = tid + j * 256;
      int kk = idx >> 5;
      int cc = (idx & 31) << 2;
      *reinterpret_cast<float4*>(&B[kk][cc]) =
          *reinterpret_cast<const float4*>(W + kk * 128 + cc);
    }
    __syncthreads();
#pragma unroll 8
    for (int kk = 0; kk < 32; ++kk) {
      float a = A[kk][lane];
      float4 b0 = *reinterpret_cast<float4*>(&B[kk][c0 + 0]);
      float4 b1 = *reinterpret_cast<float4*>(&B[kk][c0 + 4]);
      float4 b2 = *reinterpret_cast<float4*>(&B[kk][c0 + 8]);
      float4 b3 = *reinterpret_cast<float4*>(&B[kk][c0 + 12]);
      float4 b4 = *reinterpret_cast<float4*>(&B[kk][c0 + 16]);
      float4 b5 = *reinterpret_cast<float4*>(&B[kk][c0 + 20]);
      float4 b6 = *reinterpret_cast<float4*>(&B[kk][c0 + 24]);
      float4 b7 = *reinterpret_cast<float4*>(&B[kk][c0 + 28]);
      acc[0]  = fmaf(a, b0.x, acc[0]);  acc[1]  = fmaf(a, b0.y, acc[1]);
      acc[2]  = fmaf(a, b0.z, acc[2]);  acc[3]  = fmaf(a, b0.w, acc[3]);
      acc[4]  = fmaf(a, b1.x, acc[4]);  acc[5]  = fmaf(a, b1.y, acc[5]);
      acc[6]  = fmaf(a, b1.z, acc[6]);  acc[7]  = fmaf(a, b1.w, acc[7]);
      acc[8]  = fmaf(a, b2.x, acc[8]);  acc[9]  = fmaf(a, b2.y, acc[9]);
      acc[10] = fmaf(a, b2.z, acc[10]); acc[11] = fmaf(a, b2.w, acc[11]);
      acc[12] = fmaf(a, b3.x, acc[12]); acc[13] = fmaf(a, b3.y, acc[13]);
      acc[14] = fmaf(a, b3.z, acc[14]); acc[15] = fmaf(a, b3.w, acc[15]);
      acc[16] = fmaf(a, b4.x, acc[16]); acc[17] = fmaf(a, b4.y, acc[17]);
      acc[18] = fmaf(a, b4.z, acc[18]); acc[19] = fmaf(a, b4.w, acc[19]);
      acc[20] = fmaf(a, b5.x, acc[20]); acc[21] = fmaf(a, b5.y, acc[21]);
      acc[22] = fmaf(a, b5.z, acc[22]); acc[23] = fmaf(a, b5.w, acc[23]);
      acc[24] = fmaf(a, b6.x, acc[24]); acc[25] = fmaf(a, b6.y, acc[25]);
      acc[26] = fmaf(a, b6.z, acc[26]); acc[27] = fmaf(a, b6.w, acc[27]);
      acc[28] = fmaf(a, b7.x, acc[28]); acc[29] = fmaf(a, b7.y, acc[29]);
      acc[30] = fmaf(a, b7.z, acc[30]); acc[31] = fmaf(a, b7.w, acc[31]);
    }
  }

  int node = m0 + lane;
  if (node >= M) return;
#pragma unroll
  for (int j = 0; j < 8; ++j) {
    float4 bv = *reinterpret_cast<const float4*>(bias + c0 + j * 4);
    float4 r;
    r.x = acc[j * 4 + 0] + bv.x;
    r.y = acc[j * 4 + 1] + bv.y;
    r.z = acc[j * 4 + 2] + bv.z;
    r.w = acc[j * 4 + 3] + bv.w;
    if (RELU) {
      r.x = fmaxf(r.x, 0.f); r.y = fmaxf(r.y, 0.f);
      r.z = fmaxf(r.z, 0.f); r.w = fmaxf(r.w, 0.f);
    }
    *reinterpret_cast<float4*>(out + (size_t)node * 128 + c0 + j * 4) = r;
  }
}

// out = h @ Wout + bout ; lane = node, wave = 16-col group, acc[16].
__global__ __launch_bounds__(256) void k_out_gemm(
    const float* __restrict__ h, const float* __restrict__ Wout,
    const float* __restrict__ bias, float* __restrict__ out, int M) {
  __shared__ float A[32][65];
  __shared__ float B[32][68];
  const int tid = threadIdx.x;
  const int lane = tid & 63;
  const int c0 = (tid >> 6) * 16;
  const int m0 = blockIdx.x * 64;
  float acc[16] = {};
  for (int k0 = 0; k0 < 128; k0 += 32) {
    __syncthreads();
#pragma unroll
    for (int j = 0; j < 2; ++j) {
      int idx = tid + j * 256;
      int r = idx >> 3;
      int c = (idx & 7) << 2;
      int n = m0 + r;
      if (n >= M) n = M - 1;
      float4 v = *reinterpret_cast<const float4*>(h + (size_t)n * 128 + k0 + c);
      A[c + 0][r] = v.x; A[c + 1][r] = v.y; A[c + 2][r] = v.z; A[c + 3][r] = v.w;
    }
#pragma unroll
    for (int j = 0; j < 2; ++j) {
      int idx = tid + j * 256;       // 32x64 floats
      int kk = idx >> 4;
      int cc = (idx & 15) << 2;
      *reinterpret_cast<float4*>(&B[kk][cc]) =
          *reinterpret_cast<const float4*>(Wout + (size_t)(k0 + kk) * 64 + cc);
    }
    __syncthreads();
#pragma unroll 8
    for (int kk = 0; kk < 32; ++kk) {
      float a = A[kk][lane];
      float4 b0 = *reinterpret_cast<float4*>(&B[kk][c0 + 0]);
      float4 b1 = *reinterpret_cast<float4*>(&B[kk][c0 + 4]);
      float4 b2 = *reinterpret_cast<float4*>(&B[kk][c0 + 8]);
      float4 b3 = *reinterpret_cast<float4*>(&B[kk][c0 + 12]);
      acc[0]  = fmaf(a, b0.x, acc[0]);  acc[1]  = fmaf(a, b0.y, acc[1]);
      acc[2]  = fmaf(a, b0.z, acc[2]);  acc[3]  = fmaf(a, b0.w, acc[3]);
      acc[4]  = fmaf(a, b1.x, acc[4]);  acc[5]  = fmaf(a, b1.y, acc[5]);
      acc[6]  = fmaf(a, b1.z, acc[6]);  acc[7]  = fmaf(a, b1.w, acc[7]);
      acc[8]  = fmaf(a, b2.x, acc[8]);  acc[9]  = fmaf(a, b2.y, acc[9]);
      acc[10] = fmaf(a, b2.z, acc[10]); acc[11] = fmaf(a, b2.w, acc[11]);
      acc[12] = fmaf(a, b3.x, acc[12]); acc[13] = fmaf(a, b3.y, acc[13]);
      acc[14] = fmaf(a, b3.z, acc[14]); acc[15] = fmaf(a, b3.w, acc[15]);
    }
  }
  int node = m0 + lane;
  if (node >= M) return;
#pragma unroll
  for (int j = 0; j < 4; ++j) {
    float4 bv = *reinterpret_cast<const float4*>(bias + c0 + j * 4);
    float4 r;
    r.x = acc[j * 4 + 0] + bv.x;
    r.y = acc[j * 4 + 1] + bv.y;
    r.z = acc[j * 4 + 2] + bv.z;
    r.w = acc[j * 4 + 3] + bv.w;
    *reinterpret_cast<float4*>(out + (size_t)node * 64 + c0 + j * 4) = r;
  }
}

extern "C" void kernel_launch(void* const* d_in, const int* in_sizes, int n_in,
                              void* d_out, int out_size, void* d_ws, size_t ws_size,
                              hipStream_t stream) {
  const float* x    = (const float*)d_in[0];
  const int*   ei   = (const int*)d_in[1];
  const float* W1l  = (const float*)d_in[2];
  const float* W1r  = (const float*)d_in[3];
  const float* b1   = (const float*)d_in[4];
  const float* W2l  = (const float*)d_in[5];
  const float* W2r  = (const float*)d_in[6];
  const float* b2   = (const float*)d_in[7];
  const float* Wout = (const float*)d_in[8];
  const float* bout = (const float*)d_in[9];
  float* out = (float*)d_out;

  const int N = in_sizes[0] / 128;
  const int E = in_sizes[1] / 2;
  const int* src = ei;
  const int* dst = ei + E;

  // Workspace layout byte-identical to round 2 (proven fit).
  auto align = [](size_t b) { return (b + 255) & ~(size_t)255; };
  char* p = (char*)d_ws;
  int* cnt     = (int*)p;   p += align((size_t)N * 4);
  int* rowptr  = (int*)p;   p += align((size_t)(N + 1) * 4);
  int* cursor  = (int*)p;   p += align((size_t)N * 4);
  int* csr_src = (int*)p;   p += align((size_t)E * 4);
  float* bufA  = (float*)p; p += (size_t)N * 128 * 4;
  float* bufB  = (float*)p;
  // Scan scratch lives in bufA's head (dead until k_agg overwrites it).
  int* blockSums = (int*)bufA;
  int* blockOff  = blockSums + 64;

  hipMemsetAsync(cnt, 0, (size_t)N * 4, stream);

  const int nb = (N + 1023) / 1024;  // 40
  const int gemmBlocks = (N + 63) / 64;
  const int aggBlocks = (N + 3) / 4;

  // CSR build: hist -> parallel scan -> fill
  k_hist<<<(E + 255) / 256, 256, 0, stream>>>(dst, cnt, E);
  k_bsum<<<nb, 1024, 0, stream>>>(cnt, blockSums, N);
  k_bscan<<<1, 64, 0, stream>>>(blockSums, blockOff, rowptr, nb, N);
  k_escan<<<nb, 1024, 0, stream>>>(cnt, blockOff, rowptr, cursor, N);
  k_fill<<<(E + 255) / 256, 256, 0, stream>>>(src, dst, cursor, csr_src, E);

  // Layer 1
  k_agg<<<aggBlocks, 256, 0, stream>>>(x, rowptr, csr_src, bufA, N);
  k_sage_gemm<true><<<gemmBlocks, 256, 0, stream>>>(bufA, x, W1l, W1r, b1, bufB, N);

  // Layer 2
  k_agg<<<aggBlocks, 256, 0, stream>>>(bufB, rowptr, csr_src, bufA, N);
  k_sage_gemm<true><<<gemmBlocks, 256, 0, stream>>>(bufA, bufB, W2l, W2r, b2, bufB, N);

  // Output projection
  k_out_gemm<<<gemmBlocks, 256, 0, stream>>>(bufB, Wout, bout, out, N);
}

// Round 8
// 323.243 us; speedup vs baseline: 1.0839x; 1.0839x over previous
//
#include <hip/hip_runtime.h>

// GraphSAGE: 2x SAGEConv(mean) + ReLU, then linear out.
// N=40000, E=640000, IN=H=128, OUT=64. ALL-f32 (round-2 numerics, proven).
// Round 8: LDS-bytes/FMA model (r5=1.5 -> 44% ceiling, r7=4.1 -> 16%).
// Fix: 8x8 register blocking -> 1.0 B/FMA (ceiling ~66%). sage: 128 thr,
// BM=64 BN=128; out: 64 thr, BM=BN=64. Same per-output fmaf chain as r5
// (bit-identical). k_agg: float4 lanes, 8 rows in flight.

__global__ __launch_bounds__(256) void k_hist(const int* __restrict__ dst,
                                              int* __restrict__ cnt, int E) {
  int e = blockIdx.x * 256 + threadIdx.x;
  if (e < E) atomicAdd(&cnt[dst[e]], 1);
}

__global__ __launch_bounds__(1024) void k_bsum(const int* __restrict__ cnt,
                                               int* __restrict__ blockSums, int N) {
  __shared__ int ws[16];
  int i = blockIdx.x * 1024 + threadIdx.x;
  int v = (i < N) ? cnt[i] : 0;
#pragma unroll
  for (int d = 32; d > 0; d >>= 1) v += __shfl_xor(v, d, 64);
  if ((threadIdx.x & 63) == 0) ws[threadIdx.x >> 6] = v;
  __syncthreads();
  if (threadIdx.x == 0) {
    int s = 0;
#pragma unroll
    for (int w = 0; w < 16; ++w) s += ws[w];
    blockSums[blockIdx.x] = s;
  }
}

__global__ __launch_bounds__(64) void k_bscan(const int* __restrict__ blockSums,
                                              int* __restrict__ blockOff,
                                              int* __restrict__ rowptr, int nb, int N) {
  if (threadIdx.x == 0) {
    int run = 0;
    for (int i = 0; i < nb; ++i) {
      blockOff[i] = run;
      run += blockSums[i];
    }
    rowptr[N] = run;
  }
}

__global__ __launch_bounds__(1024) void k_escan(const int* __restrict__ cnt,
                                                const int* __restrict__ blockOff,
                                                int* __restrict__ rowptr,
                                                int* __restrict__ cursor, int N) {
  __shared__ int warpSums[16];
  const int tid = threadIdx.x;
  const int lane = tid & 63, wid = tid >> 6;
  int i = blockIdx.x * 1024 + tid;
  int v = (i < N) ? cnt[i] : 0;
  int s = v;
#pragma unroll
  for (int d = 1; d < 64; d <<= 1) {
    int t = __shfl_up(s, d, 64);
    if (lane >= d) s += t;
  }
  if (lane == 63) warpSums[wid] = s;
  __syncthreads();
  if (tid < 16) {
    int w = warpSums[tid];
#pragma unroll
    for (int d = 1; d < 16; d <<= 1) {
      int t = __shfl_up(w, d, 16);
      if (tid >= d) w += t;
    }
    warpSums[tid] = w;
  }
  __syncthreads();
  int ex = blockOff[blockIdx.x] + (wid ? warpSums[wid - 1] : 0) + s - v;
  if (i < N) {
    rowptr[i] = ex;
    cursor[i] = ex;
  }
}

__global__ __launch_bounds__(256) void k_fill(const int* __restrict__ src,
                                              const int* __restrict__ dst,
                                              int* __restrict__ cursor,
                                              int* __restrict__ csr_src, int E) {
  int e = blockIdx.x * 256 + threadIdx.x;
  if (e < E) {
    int pos = atomicAdd(&cursor[dst[e]], 1);
    csr_src[pos] = src[e];
  }
}

// One wave per node: mean of f32 neighbor rows (128 feats).
// 32-lane halves read full rows as float4/lane; 4 rows per half in flight
// (8 total). Halves combined via shfl_xor(32) at the end.
__global__ __launch_bounds__(256) void k_agg(const float* __restrict__ feat,
                                             const int* __restrict__ rowptr,
                                             const int* __restrict__ csr_src,
                                             float* __restrict__ agg, int N) {
  int node = (blockIdx.x * 256 + threadIdx.x) >> 6;
  if (node >= N) return;
  const int lane = threadIdx.x & 63;
  const int half = lane >> 5;          // 0: even rows, 1: odd rows
  const int c = (lane & 31) * 4;       // float4 column base
  const int beg = rowptr[node];
  const int deg = rowptr[node + 1] - beg;
  float4 a0 = {0.f, 0.f, 0.f, 0.f}, a1 = a0, a2 = a0, a3 = a0;
  int j = 0;
  for (; j + 7 < deg; j += 8) {
    int i0 = csr_src[beg + j + 0 + half];
    int i1 = csr_src[beg + j + 2 + half];
    int i2 = csr_src[beg + j + 4 + half];
    int i3 = csr_src[beg + j + 6 + half];
    float4 v0 = *reinterpret_cast<const float4*>(feat + (size_t)i0 * 128 + c);
    float4 v1 = *reinterpret_cast<const float4*>(feat + (size_t)i1 * 128 + c);
    float4 v2 = *reinterpret_cast<const float4*>(feat + (size_t)i2 * 128 + c);
    float4 v3 = *reinterpret_cast<const float4*>(feat + (size_t)i3 * 128 + c);
    a0.x += v0.x; a0.y += v0.y; a0.z += v0.z; a0.w += v0.w;
    a1.x += v1.x; a1.y += v1.y; a1.z += v1.z; a1.w += v1.w;
    a2.x += v2.x; a2.y += v2.y; a2.z += v2.z; a2.w += v2.w;
    a3.x += v3.x; a3.y += v3.y; a3.z += v3.z; a3.w += v3.w;
  }
  for (; j + half < deg; j += 2) {
    int i0 = csr_src[beg + j + half];
    float4 v0 = *reinterpret_cast<const float4*>(feat + (size_t)i0 * 128 + c);
    a0.x += v0.x; a0.y += v0.y; a0.z += v0.z; a0.w += v0.w;
  }
  a0.x += a1.x + a2.x + a3.x;
  a0.y += a1.y + a2.y + a3.y;
  a0.z += a1.z + a2.z + a3.z;
  a0.w += a1.w + a2.w + a3.w;
  a0.x += __shfl_xor(a0.x, 32);
  a0.y += __shfl_xor(a0.y, 32);
  a0.z += __shfl_xor(a0.z, 32);
  a0.w += __shfl_xor(a0.w, 32);
  if (half == 0) {
    float invd = 1.0f / fmaxf((float)deg, 1.0f);
    float4 o = {a0.x * invd, a0.y * invd, a0.z * invd, a0.w * invd};
    *reinterpret_cast<float4*>(agg + (size_t)node * 128 + c) = o;
  }
}

// Fused SAGE layer: out = relu([agg | root] @ [Wl; Wr] + b)
// BM=64 nodes x BN=128 cols, 128 threads, each 8 nodes x 8 cols (1.0 B/FMA).
// K order identical to r5 (bit-identical output).
template <bool RELU>
__global__ __launch_bounds__(128) void k_sage_gemm(
    const float* __restrict__ agg, const float* __restrict__ root,
    const float* __restrict__ Wl, const float* __restrict__ Wr,
    const float* __restrict__ bias, float* __restrict__ out, int M) {
  __shared__ float A[32][68];    // [kk][node]
  __shared__ float B[32][132];   // [kk][col]
  const int tid = threadIdx.x;
  const int tx = tid & 15;   // col group: cols tx*8 .. +7
  const int ty = tid >> 4;   // node group: nodes ty*8 .. +7
  const int m0 = blockIdx.x * 64;
  float acc[8][8] = {};

  for (int k0 = 0; k0 < 256; k0 += 32) {
    __syncthreads();
    const bool isAgg = (k0 < 128);
    const float* Asrc = isAgg ? agg : root;
    const int kbase = isAgg ? k0 : (k0 - 128);
    // Stage A: 64 rows x 32 k, transposed (512 float4s / 128 thr = 4 each)
#pragma unroll
    for (int j = 0; j < 4; ++j) {
      int idx = tid + j * 128;
      int r = idx >> 3;
      int c = (idx & 7) << 2;
      int n = m0 + r;
      if (n >= M) n = M - 1;
      float4 v = *reinterpret_cast<const float4*>(Asrc + (size_t)n * 128 + kbase + c);
      A[c + 0][r] = v.x; A[c + 1][r] = v.y; A[c + 2][r] = v.z; A[c + 3][r] = v.w;
    }
    // Stage B: 32 k x 128 cols (1024 float4s / 128 thr = 8 each)
    const float* W = isAgg ? (Wl + (size_t)k0 * 128) : (Wr + (size_t)(k0 - 128) * 128);
#pragma unroll
    for (int j = 0; j < 8; ++j) {
      int idx = tid + j * 128;
      int kk = idx >> 5;
      int cc = (idx & 31) << 2;
      *reinterpret_cast<float4*>(&B[kk][cc]) =
          *reinterpret_cast<const float4*>(W + kk * 128 + cc);
    }
    __syncthreads();
#pragma unroll 4
    for (int kk = 0; kk < 32; ++kk) {
      float4 a0 = *reinterpret_cast<float4*>(&A[kk][ty * 8]);
      float4 a1 = *reinterpret_cast<float4*>(&A[kk][ty * 8 + 4]);
      float4 b0 = *reinterpret_cast<float4*>(&B[kk][tx * 8]);
      float4 b1 = *reinterpret_cast<float4*>(&B[kk][tx * 8 + 4]);
      float a[8] = {a0.x, a0.y, a0.z, a0.w, a1.x, a1.y, a1.z, a1.w};
      float b[8] = {b0.x, b0.y, b0.z, b0.w, b1.x, b1.y, b1.z, b1.w};
#pragma unroll
      for (int i = 0; i < 8; ++i)
#pragma unroll
        for (int jj = 0; jj < 8; ++jj)
          acc[i][jj] = fmaf(a[i], b[jj], acc[i][jj]);
    }
  }

  float4 bv0 = *reinterpret_cast<const float4*>(bias + tx * 8);
  float4 bv1 = *reinterpret_cast<const float4*>(bias + tx * 8 + 4);
  float bb[8] = {bv0.x, bv0.y, bv0.z, bv0.w, bv1.x, bv1.y, bv1.z, bv1.w};
#pragma unroll
  for (int i = 0; i < 8; ++i) {
    int node = m0 + ty * 8 + i;
    if (node >= M) continue;
    float r[8];
#pragma unroll
    for (int jj = 0; jj < 8; ++jj) {
      r[jj] = acc[i][jj] + bb[jj];
      if (RELU) r[jj] = fmaxf(r[jj], 0.f);
    }
    float4 o0 = {r[0], r[1], r[2], r[3]};
    float4 o1 = {r[4], r[5], r[6], r[7]};
    *reinterpret_cast<float4*>(out + (size_t)node * 128 + tx * 8) = o0;
    *reinterpret_cast<float4*>(out + (size_t)node * 128 + tx * 8 + 4) = o1;
  }
}

// out = h @ Wout + bout ; BM=64 x BN=64, 64 threads, each 8x8.
__global__ __launch_bounds__(64) void k_out_gemm(
    const float* __restrict__ h, const float* __restrict__ Wout,
    const float* __restrict__ bias, float* __restrict__ out, int M) {
  __shared__ float A[32][68];
  __shared__ float B[32][68];
  const int tid = threadIdx.x;
  const int tx = tid & 7;    // col group: cols tx*8 .. +7
  const int ty = tid >> 3;   // node group: nodes ty*8 .. +7
  const int m0 = blockIdx.x * 64;
  float acc[8][8] = {};
  for (int k0 = 0; k0 < 128; k0 += 32) {
    __syncthreads();
#pragma unroll
    for (int j = 0; j < 8; ++j) {
      int idx = tid + j * 64;
      int r = idx >> 3;
      int c = (idx & 7) << 2;
      int n = m0 + r;
      if (n >= M) n = M - 1;
      float4 v = *reinterpret_cast<const float4*>(h + (size_t)n * 128 + k0 + c);
      A[c + 0][r] = v.x; A[c + 1][r] = v.y; A[c + 2][r] = v.z; A[c + 3][r] = v.w;
    }
#pragma unroll
    for (int j = 0; j < 8; ++j) {
      int idx = tid + j * 64;       // 512 float4s = 32x64
      int kk = idx >> 4;
      int cc = (idx & 15) << 2;
      *reinterpret_cast<float4*>(&B[kk][cc]) =
          *reinterpret_cast<const float4*>(Wout + (size_t)(k0 + kk) * 64 + cc);
    }
    __syncthreads();
#pragma unroll 4
    for (int kk = 0; kk < 32; ++kk) {
      float4 a0 = *reinterpret_cast<float4*>(&A[kk][ty * 8]);
      float4 a1 = *reinterpret_cast<float4*>(&A[kk][ty * 8 + 4]);
      float4 b0 = *reinterpret_cast<float4*>(&B[kk][tx * 8]);
      float4 b1 = *reinterpret_cast<float4*>(&B[kk][tx * 8 + 4]);
      float a[8] = {a0.x, a0.y, a0.z, a0.w, a1.x, a1.y, a1.z, a1.w};
      float b[8] = {b0.x, b0.y, b0.z, b0.w, b1.x, b1.y, b1.z, b1.w};
#pragma unroll
      for (int i = 0; i < 8; ++i)
#pragma unroll
        for (int jj = 0; jj < 8; ++jj)
          acc[i][jj] = fmaf(a[i], b[jj], acc[i][jj]);
    }
  }
  float4 bv0 = *reinterpret_cast<const float4*>(bias + tx * 8);
  float4 bv1 = *reinterpret_cast<const float4*>(bias + tx * 8 + 4);
  float bb[8] = {bv0.x, bv0.y, bv0.z, bv0.w, bv1.x, bv1.y, bv1.z, bv1.w};
#pragma unroll
  for (int i = 0; i < 8; ++i) {
    int node = m0 + ty * 8 + i;
    if (node >= M) continue;
    float r[8];
#pragma unroll
    for (int jj = 0; jj < 8; ++jj) r[jj] = acc[i][jj] + bb[jj];
    float4 o0 = {r[0], r[1], r[2], r[3]};
    float4 o1 = {r[4], r[5], r[6], r[7]};
    *reinterpret_cast<float4*>(out + (size_t)node * 64 + tx * 8) = o0;
    *reinterpret_cast<float4*>(out + (size_t)node * 64 + tx * 8 + 4) = o1;
  }
}

extern "C" void kernel_launch(void* const* d_in, const int* in_sizes, int n_in,
                              void* d_out, int out_size, void* d_ws, size_t ws_size,
                              hipStream_t stream) {
  const float* x    = (const float*)d_in[0];
  const int*   ei   = (const int*)d_in[1];
  const float* W1l  = (const float*)d_in[2];
  const float* W1r  = (const float*)d_in[3];
  const float* b1   = (const float*)d_in[4];
  const float* W2l  = (const float*)d_in[5];
  const float* W2r  = (const float*)d_in[6];
  const float* b2   = (const float*)d_in[7];
  const float* Wout = (const float*)d_in[8];
  const float* bout = (const float*)d_in[9];
  float* out = (float*)d_out;

  const int N = in_sizes[0] / 128;
  const int E = in_sizes[1] / 2;
  const int* src = ei;
  const int* dst = ei + E;

  // Workspace layout byte-identical to round 2 (proven fit).
  auto align = [](size_t b) { return (b + 255) & ~(size_t)255; };
  char* p = (char*)d_ws;
  int* cnt     = (int*)p;   p += align((size_t)N * 4);
  int* rowptr  = (int*)p;   p += align((size_t)(N + 1) * 4);
  int* cursor  = (int*)p;   p += align((size_t)N * 4);
  int* csr_src = (int*)p;   p += align((size_t)E * 4);
  float* bufA  = (float*)p; p += (size_t)N * 128 * 4;
  float* bufB  = (float*)p;
  // Scan scratch lives in bufA's head (dead until k_agg overwrites it).
  int* blockSums = (int*)bufA;
  int* blockOff  = blockSums + 64;

  hipMemsetAsync(cnt, 0, (size_t)N * 4, stream);

  const int nb = (N + 1023) / 1024;  // 40
  const int gemmBlocks = (N + 63) / 64;
  const int aggBlocks = (N + 3) / 4;

  // CSR build: hist -> parallel scan -> fill
  k_hist<<<(E + 255) / 256, 256, 0, stream>>>(dst, cnt, E);
  k_bsum<<<nb, 1024, 0, stream>>>(cnt, blockSums, N);
  k_bscan<<<1, 64, 0, stream>>>(blockSums, blockOff, rowptr, nb, N);
  k_escan<<<nb, 1024, 0, stream>>>(cnt, blockOff, rowptr, cursor, N);
  k_fill<<<(E + 255) / 256, 256, 0, stream>>>(src, dst, cursor, csr_src, E);

  // Layer 1
  k_agg<<<aggBlocks, 256, 0, stream>>>(x, rowptr, csr_src, bufA, N);
  k_sage_gemm<true><<<gemmBlocks, 128, 0, stream>>>(bufA, x, W1l, W1r, b1, bufB, N);

  // Layer 2
  k_agg<<<aggBlocks, 256, 0, stream>>>(bufB, rowptr, csr_src, bufA, N);
  k_sage_gemm<true><<<gemmBlocks, 128, 0, stream>>>(bufA, bufB, W2l, W2r, b2, bufB, N);

  // Output projection
  k_out_gemm<<<gemmBlocks, 64, 0, stream>>>(bufB, Wout, bout, out, N);
}

// Round 9
// 223.989 us; speedup vs baseline: 1.5642x; 1.4431x over previous
//
#include <hip/hip_runtime.h>

// GraphSAGE: 2x SAGEConv(mean) + ReLU, then linear out.
// N=40000, E=640000, IN=H=128, OUT=64.
// Round 9: sage GEMMs via MFMA bf16 hi/lo split (A*W ~= Ah*Wh + Ah*Wl + Al*Wh,
// error ~2^-16 rel — true f32-class, unlike r3/r4's 2^-8 quantization).
// No LDS, no barriers: weights pre-packed in fragment order (reuse cnt/cursor
// space post-CSR), A read f32 + split on the fly (VALU overlaps MFMA pipe).
// k_agg/out_gemm/CSR from proven r5/r8. Workspace layout identical to r2.

typedef __attribute__((ext_vector_type(8))) short short8v;   // 8 bf16
typedef __attribute__((ext_vector_type(4))) float f32x4;

static __device__ __forceinline__ unsigned short f2bf(float f) {
  unsigned u = __float_as_uint(f);
  u += 0x7fffu + ((u >> 16) & 1u);   // RNE
  return (unsigned short)(u >> 16);
}
static __device__ __forceinline__ float bf2f(unsigned short h) {
  return __uint_as_float(((unsigned)h) << 16);
}

__global__ __launch_bounds__(256) void k_hist(const int* __restrict__ dst,
                                              int* __restrict__ cnt, int E) {
  int e = blockIdx.x * 256 + threadIdx.x;
  if (e < E) atomicAdd(&cnt[dst[e]], 1);
}

__global__ __launch_bounds__(1024) void k_bsum(const int* __restrict__ cnt,
                                               int* __restrict__ blockSums, int N) {
  __shared__ int ws[16];
  int i = blockIdx.x * 1024 + threadIdx.x;
  int v = (i < N) ? cnt[i] : 0;
#pragma unroll
  for (int d = 32; d > 0; d >>= 1) v += __shfl_xor(v, d, 64);
  if ((threadIdx.x & 63) == 0) ws[threadIdx.x >> 6] = v;
  __syncthreads();
  if (threadIdx.x == 0) {
    int s = 0;
#pragma unroll
    for (int w = 0; w < 16; ++w) s += ws[w];
    blockSums[blockIdx.x] = s;
  }
}

__global__ __launch_bounds__(64) void k_bscan(const int* __restrict__ blockSums,
                                              int* __restrict__ blockOff,
                                              int* __restrict__ rowptr, int nb, int N) {
  if (threadIdx.x == 0) {
    int run = 0;
    for (int i = 0; i < nb; ++i) {
      blockOff[i] = run;
      run += blockSums[i];
    }
    rowptr[N] = run;
  }
}

__global__ __launch_bounds__(1024) void k_escan(const int* __restrict__ cnt,
                                                const int* __restrict__ blockOff,
                                                int* __restrict__ rowptr,
                                                int* __restrict__ cursor, int N) {
  __shared__ int warpSums[16];
  const int tid = threadIdx.x;
  const int lane = tid & 63, wid = tid >> 6;
  int i = blockIdx.x * 1024 + tid;
  int v = (i < N) ? cnt[i] : 0;
  int s = v;
#pragma unroll
  for (int d = 1; d < 64; d <<= 1) {
    int t = __shfl_up(s, d, 64);
    if (lane >= d) s += t;
  }
  if (lane == 63) warpSums[wid] = s;
  __syncthreads();
  if (tid < 16) {
    int w = warpSums[tid];
#pragma unroll
    for (int d = 1; d < 16; d <<= 1) {
      int t = __shfl_up(w, d, 16);
      if (tid >= d) w += t;
    }
    warpSums[tid] = w;
  }
  __syncthreads();
  int ex = blockOff[blockIdx.x] + (wid ? warpSums[wid - 1] : 0) + s - v;
  if (i < N) {
    rowptr[i] = ex;
    cursor[i] = ex;
  }
}

__global__ __launch_bounds__(256) void k_fill(const int* __restrict__ src,
                                              const int* __restrict__ dst,
                                              int* __restrict__ cursor,
                                              int* __restrict__ csr_src, int E) {
  int e = blockIdx.x * 256 + threadIdx.x;
  if (e < E) {
    int pos = atomicAdd(&cursor[dst[e]], 1);
    csr_src[pos] = src[e];
  }
}

// Pack W = [Wl;Wr] (256x128 f32) into MFMA B-fragment order, bf16 hi/lo.
// Element (s,n,l,j): k = s*32 + (l>>4)*8 + j, col = n*16 + (l&15).
// wh/wl index = ((s*8+n)*64 + l)*8 + j.  4096 threads.
__global__ __launch_bounds__(256) void k_packw(const float* __restrict__ Wl,
                                               const float* __restrict__ Wr,
                                               ushort* __restrict__ wh,
                                               ushort* __restrict__ wl_) {
  int t = blockIdx.x * 256 + threadIdx.x;
  if (t >= 8 * 8 * 64) return;
  int l = t & 63;
  int n = (t >> 6) & 7;
  int s = t >> 9;
  int col = n * 16 + (l & 15);
  int kb = s * 32 + ((l >> 4) * 8);
  size_t base = ((size_t)(s * 8 + n) * 64 + l) * 8;
#pragma unroll
  for (int j = 0; j < 8; ++j) {
    int k = kb + j;
    float w = (k < 128) ? Wl[(size_t)k * 128 + col] : Wr[(size_t)(k - 128) * 128 + col];
    unsigned short hb = f2bf(w);
    wh[base + j] = hb;
    wl_[base + j] = f2bf(w - bf2f(hb));
  }
}

// One wave per node: mean of f32 neighbor rows (128 feats).
// 32-lane halves read full rows as float4/lane; 8 rows in flight. (r8-proven)
__global__ __launch_bounds__(256) void k_agg(const float* __restrict__ feat,
                                             const int* __restrict__ rowptr,
                                             const int* __restrict__ csr_src,
                                             float* __restrict__ agg, int N) {
  int node = (blockIdx.x * 256 + threadIdx.x) >> 6;
  if (node >= N) return;
  const int lane = threadIdx.x & 63;
  const int half = lane >> 5;
  const int c = (lane & 31) * 4;
  const int beg = rowptr[node];
  const int deg = rowptr[node + 1] - beg;
  float4 a0 = {0.f, 0.f, 0.f, 0.f}, a1 = a0, a2 = a0, a3 = a0;
  int j = 0;
  for (; j + 7 < deg; j += 8) {
    int i0 = csr_src[beg + j + 0 + half];
    int i1 = csr_src[beg + j + 2 + half];
    int i2 = csr_src[beg + j + 4 + half];
    int i3 = csr_src[beg + j + 6 + half];
    float4 v0 = *reinterpret_cast<const float4*>(feat + (size_t)i0 * 128 + c);
    float4 v1 = *reinterpret_cast<const float4*>(feat + (size_t)i1 * 128 + c);
    float4 v2 = *reinterpret_cast<const float4*>(feat + (size_t)i2 * 128 + c);
    float4 v3 = *reinterpret_cast<const float4*>(feat + (size_t)i3 * 128 + c);
    a0.x += v0.x; a0.y += v0.y; a0.z += v0.z; a0.w += v0.w;
    a1.x += v1.x; a1.y += v1.y; a1.z += v1.z; a1.w += v1.w;
    a2.x += v2.x; a2.y += v2.y; a2.z += v2.z; a2.w += v2.w;
    a3.x += v3.x; a3.y += v3.y; a3.z += v3.z; a3.w += v3.w;
  }
  for (; j + half < deg; j += 2) {
    int i0 = csr_src[beg + j + half];
    float4 v0 = *reinterpret_cast<const float4*>(feat + (size_t)i0 * 128 + c);
    a0.x += v0.x; a0.y += v0.y; a0.z += v0.z; a0.w += v0.w;
  }
  a0.x += a1.x + a2.x + a3.x;
  a0.y += a1.y + a2.y + a3.y;
  a0.z += a1.z + a2.z + a3.z;
  a0.w += a1.w + a2.w + a3.w;
  a0.x += __shfl_xor(a0.x, 32);
  a0.y += __shfl_xor(a0.y, 32);
  a0.z += __shfl_xor(a0.z, 32);
  a0.w += __shfl_xor(a0.w, 32);
  if (half == 0) {
    float invd = 1.0f / fmaxf((float)deg, 1.0f);
    float4 o = {a0.x * invd, a0.y * invd, a0.z * invd, a0.w * invd};
    *reinterpret_cast<float4*>(agg + (size_t)node * 128 + c) = o;
  }
}

// Fused SAGE layer via MFMA: out = relu([agg | root] @ [Wl;Wr] + b)
// 4 waves/block, wave owns 16 rows x 128 cols (8 D-tiles of 16x16).
// k-steps s=0..7: s<4 reads agg (k=s*32..), s>=4 reads root.
// A f32 -> on-the-fly bf16 hi/lo; W pre-packed fragments (hi/lo).
// acc[n] += Ah*Wh + Ah*Wl + Al*Wh  (lo*lo dropped, ~2^-16 rel).
template <bool RELU>
__global__ __launch_bounds__(256) void k_gemm_mfma(
    const float* __restrict__ A0, const float* __restrict__ A1,
    const ushort* __restrict__ wh, const ushort* __restrict__ wl_,
    const float* __restrict__ bias, float* __restrict__ out, int M) {
  const int lane = threadIdx.x & 63;
  const int wave = threadIdx.x >> 6;
  const int row = blockIdx.x * 64 + wave * 16;     // wave's 16-row tile
  f32x4 acc[8] = {};

  for (int s = 0; s < 8; ++s) {
    const float* A = (s < 4) ? A0 : A1;
    const int kb = (s & 3) * 32;
    // A fragment: row (lane&15), k = kb + (lane>>4)*8 + j  (8 contiguous f32)
    const float* ap = A + (size_t)(row + (lane & 15)) * 128 + kb + (lane >> 4) * 8;
    float4 av0 = *reinterpret_cast<const float4*>(ap);
    float4 av1 = *reinterpret_cast<const float4*>(ap + 4);
    float av[8] = {av0.x, av0.y, av0.z, av0.w, av1.x, av1.y, av1.z, av1.w};
    short8v ah, al;
#pragma unroll
    for (int j = 0; j < 8; ++j) {
      unsigned short hb = f2bf(av[j]);
      ah[j] = (short)hb;
      al[j] = (short)f2bf(av[j] - bf2f(hb));
    }
    const size_t sbase = (size_t)s * 8 * 64 * 8 + (size_t)lane * 8;
#pragma unroll
    for (int n = 0; n < 8; ++n) {
      short8v bh = *reinterpret_cast<const short8v*>(wh + sbase + (size_t)n * 64 * 8);
      short8v bl = *reinterpret_cast<const short8v*>(wl_ + sbase + (size_t)n * 64 * 8);
      acc[n] = __builtin_amdgcn_mfma_f32_16x16x32_bf16(ah, bh, acc[n], 0, 0, 0);
      acc[n] = __builtin_amdgcn_mfma_f32_16x16x32_bf16(ah, bl, acc[n], 0, 0, 0);
      acc[n] = __builtin_amdgcn_mfma_f32_16x16x32_bf16(al, bh, acc[n], 0, 0, 0);
    }
  }

  // D: row = row + (lane>>4)*4 + r, col = n*16 + (lane&15)
  const int r0 = row + (lane >> 4) * 4;
  const int col0 = lane & 15;
#pragma unroll
  for (int n = 0; n < 8; ++n) {
    int col = n * 16 + col0;
    float bv = bias[col];
#pragma unroll
    for (int r = 0; r < 4; ++r) {
      float v = acc[n][r] + bv;
      if (RELU) v = fmaxf(v, 0.f);
      out[(size_t)(r0 + r) * 128 + col] = v;
    }
  }
}

// out = h @ Wout + bout ; tile 64x64, 256 thr, each 4x4. (r5-proven)
__global__ __launch_bounds__(256) void k_out_gemm(
    const float* __restrict__ h, const float* __restrict__ Wout,
    const float* __restrict__ bias, float* __restrict__ out, int M) {
  __shared__ float A[32][68];
  __shared__ float B[32][68];
  const int tid = threadIdx.x;
  const int tx = tid & 15;
  const int ty = tid >> 4;
  const int m0 = blockIdx.x * 64;
  float acc[4][4] = {};
  for (int k0 = 0; k0 < 128; k0 += 32) {
    __syncthreads();
#pragma unroll
    for (int j = 0; j < 2; ++j) {
      int idx = tid + j * 256;
      int r = idx >> 3;
      int c = (idx & 7) << 2;
      int n = m0 + r;
      if (n >= M) n = M - 1;
      float4 v = *reinterpret_cast<const float4*>(h + (size_t)n * 128 + k0 + c);
      A[c + 0][r] = v.x; A[c + 1][r] = v.y; A[c + 2][r] = v.z; A[c + 3][r] = v.w;
    }
#pragma unroll
    for (int j = 0; j < 2; ++j) {
      int idx = tid + j * 256;
      int kk = idx >> 4;
      int cc = (idx & 15) << 2;
      *reinterpret_cast<float4*>(&B[kk][cc]) =
          *reinterpret_cast<const float4*>(Wout + (size_t)(k0 + kk) * 64 + cc);
    }
    __syncthreads();
#pragma unroll 8
    for (int kk = 0; kk < 32; ++kk) {
      float4 b4 = *reinterpret_cast<float4*>(&B[kk][tx * 4]);
      float4 a4 = *reinterpret_cast<float4*>(&A[kk][ty * 4]);
      float a[4] = {a4.x, a4.y, a4.z, a4.w};
#pragma unroll
      for (int i = 0; i < 4; ++i) {
        acc[i][0] = fmaf(a[i], b4.x, acc[i][0]);
        acc[i][1] = fmaf(a[i], b4.y, acc[i][1]);
        acc[i][2] = fmaf(a[i], b4.z, acc[i][2]);
        acc[i][3] = fmaf(a[i], b4.w, acc[i][3]);
      }
    }
  }
  float4 bv = *reinterpret_cast<const float4*>(bias + tx * 4);
#pragma unroll
  for (int i = 0; i < 4; ++i) {
    int node = m0 + ty * 4 + i;
    if (node >= M) continue;
    float4 r;
    r.x = acc[i][0] + bv.x;
    r.y = acc[i][1] + bv.y;
    r.z = acc[i][2] + bv.z;
    r.w = acc[i][3] + bv.w;
    *reinterpret_cast<float4*>(out + (size_t)node * 64 + tx * 4) = r;
  }
}

extern "C" void kernel_launch(void* const* d_in, const int* in_sizes, int n_in,
                              void* d_out, int out_size, void* d_ws, size_t ws_size,
                              hipStream_t stream) {
  const float* x    = (const float*)d_in[0];
  const int*   ei   = (const int*)d_in[1];
  const float* W1l  = (const float*)d_in[2];
  const float* W1r  = (const float*)d_in[3];
  const float* b1   = (const float*)d_in[4];
  const float* W2l  = (const float*)d_in[5];
  const float* W2r  = (const float*)d_in[6];
  const float* b2   = (const float*)d_in[7];
  const float* Wout = (const float*)d_in[8];
  const float* bout = (const float*)d_in[9];
  float* out = (float*)d_out;

  const int N = in_sizes[0] / 128;
  const int E = in_sizes[1] / 2;
  const int* src = ei;
  const int* dst = ei + E;

  // Workspace layout byte-identical to round 2 (proven fit).
  auto align = [](size_t b) { return (b + 255) & ~(size_t)255; };
  char* p = (char*)d_ws;
  int* cnt     = (int*)p;   p += align((size_t)N * 4);
  int* rowptr  = (int*)p;   p += align((size_t)(N + 1) * 4);
  int* cursor  = (int*)p;   p += align((size_t)N * 4);
  int* csr_src = (int*)p;   p += align((size_t)E * 4);
  float* bufA  = (float*)p; p += (size_t)N * 128 * 4;
  float* bufB  = (float*)p;
  // Scan scratch in bufA head (dead until k_agg).
  int* blockSums = (int*)bufA;
  int* blockOff  = blockSums + 64;
  // Weight packs reuse cnt (dead after escan) and cursor (dead after fill):
  // each needs 2 x 64KB = 131072 B <= 160KB region.
  ushort* w1h = (ushort*)cnt;
  ushort* w1l = w1h + 8 * 8 * 64 * 8;      // +64KB
  ushort* w2h = (ushort*)cursor;
  ushort* w2l = w2h + 8 * 8 * 64 * 8;

  hipMemsetAsync(cnt, 0, (size_t)N * 4, stream);

  const int nb = (N + 1023) / 1024;  // 40
  const int gemmBlocks = (N + 63) / 64;
  const int aggBlocks = (N + 3) / 4;

  // CSR build
  k_hist<<<(E + 255) / 256, 256, 0, stream>>>(dst, cnt, E);
  k_bsum<<<nb, 1024, 0, stream>>>(cnt, blockSums, N);
  k_bscan<<<1, 64, 0, stream>>>(blockSums, blockOff, rowptr, nb, N);
  k_escan<<<nb, 1024, 0, stream>>>(cnt, blockOff, rowptr, cursor, N);
  k_fill<<<(E + 255) / 256, 256, 0, stream>>>(src, dst, cursor, csr_src, E);

  // Weight packs (after cnt/cursor are dead)
  k_packw<<<16, 256, 0, stream>>>(W1l, W1r, w1h, w1l);
  k_packw<<<16, 256, 0, stream>>>(W2l, W2r, w2h, w2l);

  // Layer 1
  k_agg<<<aggBlocks, 256, 0, stream>>>(x, rowptr, csr_src, bufA, N);
  k_gemm_mfma<true><<<gemmBlocks, 256, 0, stream>>>(bufA, x, w1h, w1l, b1, bufB, N);

  // Layer 2
  k_agg<<<aggBlocks, 256, 0, stream>>>(bufB, rowptr, csr_src, bufA, N);
  k_gemm_mfma<true><<<gemmBlocks, 256, 0, stream>>>(bufA, bufB, w2h, w2l, b2, bufB, N);

  // Output projection
  k_out_gemm<<<gemmBlocks, 256, 0, stream>>>(bufB, Wout, bout, out, N);
}

// Round 10
// 220.540 us; speedup vs baseline: 1.5887x; 1.0156x over previous
//
#include <hip/hip_runtime.h>

// GraphSAGE: 2x SAGEConv(mean) + ReLU, then linear out.
// N=40000, E=640000, IN=H=128, OUT=64.
// Round 10: r9 + (1) out-projection via MFMA hi/lo (Wout packed into cnt
// region after gemm1 frees it), (2) k_agg tail cascade (4/2/1 straight-line,
// kills serial per-row latency chain), (3) merged weight-pack launch.
// Workspace layout byte-identical to r2/r9 (proven fit).

typedef __attribute__((ext_vector_type(8))) short short8v;   // 8 bf16
typedef __attribute__((ext_vector_type(4))) float f32x4;

static __device__ __forceinline__ unsigned short f2bf(float f) {
  unsigned u = __float_as_uint(f);
  u += 0x7fffu + ((u >> 16) & 1u);   // RNE
  return (unsigned short)(u >> 16);
}
static __device__ __forceinline__ float bf2f(unsigned short h) {
  return __uint_as_float(((unsigned)h) << 16);
}

__global__ __launch_bounds__(256) void k_hist(const int* __restrict__ dst,
                                              int* __restrict__ cnt, int E) {
  int e = blockIdx.x * 256 + threadIdx.x;
  if (e < E) atomicAdd(&cnt[dst[e]], 1);
}

__global__ __launch_bounds__(1024) void k_bsum(const int* __restrict__ cnt,
                                               int* __restrict__ blockSums, int N) {
  __shared__ int ws[16];
  int i = blockIdx.x * 1024 + threadIdx.x;
  int v = (i < N) ? cnt[i] : 0;
#pragma unroll
  for (int d = 32; d > 0; d >>= 1) v += __shfl_xor(v, d, 64);
  if ((threadIdx.x & 63) == 0) ws[threadIdx.x >> 6] = v;
  __syncthreads();
  if (threadIdx.x == 0) {
    int s = 0;
#pragma unroll
    for (int w = 0; w < 16; ++w) s += ws[w];
    blockSums[blockIdx.x] = s;
  }
}

__global__ __launch_bounds__(64) void k_bscan(const int* __restrict__ blockSums,
                                              int* __restrict__ blockOff,
                                              int* __restrict__ rowptr, int nb, int N) {
  if (threadIdx.x == 0) {
    int run = 0;
    for (int i = 0; i < nb; ++i) {
      blockOff[i] = run;
      run += blockSums[i];
    }
    rowptr[N] = run;
  }
}

__global__ __launch_bounds__(1024) void k_escan(const int* __restrict__ cnt,
                                                const int* __restrict__ blockOff,
                                                int* __restrict__ rowptr,
                                                int* __restrict__ cursor, int N) {
  __shared__ int warpSums[16];
  const int tid = threadIdx.x;
  const int lane = tid & 63, wid = tid >> 6;
  int i = blockIdx.x * 1024 + tid;
  int v = (i < N) ? cnt[i] : 0;
  int s = v;
#pragma unroll
  for (int d = 1; d < 64; d <<= 1) {
    int t = __shfl_up(s, d, 64);
    if (lane >= d) s += t;
  }
  if (lane == 63) warpSums[wid] = s;
  __syncthreads();
  if (tid < 16) {
    int w = warpSums[tid];
#pragma unroll
    for (int d = 1; d < 16; d <<= 1) {
      int t = __shfl_up(w, d, 16);
      if (tid >= d) w += t;
    }
    warpSums[tid] = w;
  }
  __syncthreads();
  int ex = blockOff[blockIdx.x] + (wid ? warpSums[wid - 1] : 0) + s - v;
  if (i < N) {
    rowptr[i] = ex;
    cursor[i] = ex;
  }
}

__global__ __launch_bounds__(256) void k_fill(const int* __restrict__ src,
                                              const int* __restrict__ dst,
                                              int* __restrict__ cursor,
                                              int* __restrict__ csr_src, int E) {
  int e = blockIdx.x * 256 + threadIdx.x;
  if (e < E) {
    int pos = atomicAdd(&cursor[dst[e]], 1);
    csr_src[pos] = src[e];
  }
}

// Pack W1=[W1l;W1r] and W2=[W2l;W2r] (256x128 each) into MFMA B-fragment
// order, bf16 hi/lo. Element (s,n,l,j): k=s*32+(l>>4)*8+j, col=n*16+(l&15).
// Index = ((s*8+n)*64+l)*8+j. 8192 threads (t<4096: W1, else W2).
__global__ __launch_bounds__(256) void k_packw12(
    const float* __restrict__ W1l, const float* __restrict__ W1r,
    const float* __restrict__ W2l, const float* __restrict__ W2r,
    ushort* __restrict__ w1h, ushort* __restrict__ w1lo,
    ushort* __restrict__ w2h, ushort* __restrict__ w2lo) {
  int t = blockIdx.x * 256 + threadIdx.x;
  if (t >= 8192) return;
  const bool is2 = t >= 4096;
  int u = t & 4095;
  const float* Wl = is2 ? W2l : W1l;
  const float* Wr = is2 ? W2r : W1r;
  ushort* wh = is2 ? w2h : w1h;
  ushort* wlo = is2 ? w2lo : w1lo;
  int l = u & 63;
  int n = (u >> 6) & 7;
  int s = u >> 9;
  int col = n * 16 + (l & 15);
  int kb = s * 32 + ((l >> 4) * 8);
  size_t base = ((size_t)(s * 8 + n) * 64 + l) * 8;
#pragma unroll
  for (int j = 0; j < 8; ++j) {
    int k = kb + j;
    float w = (k < 128) ? Wl[(size_t)k * 128 + col] : Wr[(size_t)(k - 128) * 128 + col];
    unsigned short hb = f2bf(w);
    wh[base + j] = hb;
    wlo[base + j] = f2bf(w - bf2f(hb));
  }
}

// Pack Wout (128x64) into fragment order: s=0..3, n=0..3. 1024 threads.
__global__ __launch_bounds__(256) void k_packwout(const float* __restrict__ Wout,
                                                  ushort* __restrict__ wh,
                                                  ushort* __restrict__ wlo) {
  int t = blockIdx.x * 256 + threadIdx.x;
  if (t >= 1024) return;
  int l = t & 63;
  int n = (t >> 6) & 3;
  int s = t >> 8;
  int col = n * 16 + (l & 15);
  int kb = s * 32 + ((l >> 4) * 8);
  size_t base = ((size_t)(s * 4 + n) * 64 + l) * 8;
#pragma unroll
  for (int j = 0; j < 8; ++j) {
    float w = Wout[(size_t)(kb + j) * 64 + col];
    unsigned short hb = f2bf(w);
    wh[base + j] = hb;
    wlo[base + j] = f2bf(w - bf2f(hb));
  }
}

// One wave per node: mean of f32 neighbor rows (128 feats).
// 32-lane halves, float4/lane, 8 rows in flight; tail = 4/2/1 cascade
// (straight-line, <=3 dependent latency groups vs up-to-7 serial iters).
__global__ __launch_bounds__(256) void k_agg(const float* __restrict__ feat,
                                             const int* __restrict__ rowptr,
                                             const int* __restrict__ csr_src,
                                             float* __restrict__ agg, int N) {
  int node = (blockIdx.x * 256 + threadIdx.x) >> 6;
  if (node >= N) return;
  const int lane = threadIdx.x & 63;
  const int half = lane >> 5;
  const int c = (lane & 31) * 4;
  const int beg = rowptr[node];
  const int deg = rowptr[node + 1] - beg;
  float4 a0 = {0.f, 0.f, 0.f, 0.f}, a1 = a0, a2 = a0, a3 = a0;
  int j = 0;
  for (; j + 7 < deg; j += 8) {
    int i0 = csr_src[beg + j + 0 + half];
    int i1 = csr_src[beg + j + 2 + half];
    int i2 = csr_src[beg + j + 4 + half];
    int i3 = csr_src[beg + j + 6 + half];
    float4 v0 = *reinterpret_cast<const float4*>(feat + (size_t)i0 * 128 + c);
    float4 v1 = *reinterpret_cast<const float4*>(feat + (size_t)i1 * 128 + c);
    float4 v2 = *reinterpret_cast<const float4*>(feat + (size_t)i2 * 128 + c);
    float4 v3 = *reinterpret_cast<const float4*>(feat + (size_t)i3 * 128 + c);
    a0.x += v0.x; a0.y += v0.y; a0.z += v0.z; a0.w += v0.w;
    a1.x += v1.x; a1.y += v1.y; a1.z += v1.z; a1.w += v1.w;
    a2.x += v2.x; a2.y += v2.y; a2.z += v2.z; a2.w += v2.w;
    a3.x += v3.x; a3.y += v3.y; a3.z += v3.z; a3.w += v3.w;
  }
  if (j + 3 < deg) {   // 4 rows: 2 per half
    int i0 = csr_src[beg + j + 0 + half];
    int i1 = csr_src[beg + j + 2 + half];
    float4 v0 = *reinterpret_cast<const float4*>(feat + (size_t)i0 * 128 + c);
    float4 v1 = *reinterpret_cast<const float4*>(feat + (size_t)i1 * 128 + c);
    a0.x += v0.x; a0.y += v0.y; a0.z += v0.z; a0.w += v0.w;
    a1.x += v1.x; a1.y += v1.y; a1.z += v1.z; a1.w += v1.w;
    j += 4;
  }
  if (j + 1 < deg) {   // 2 rows: 1 per half
    int i0 = csr_src[beg + j + half];
    float4 v0 = *reinterpret_cast<const float4*>(feat + (size_t)i0 * 128 + c);
    a2.x += v0.x; a2.y += v0.y; a2.z += v0.z; a2.w += v0.w;
    j += 2;
  }
  if (j < deg && half == 0) {   // last row: half 0 only
    int i0 = csr_src[beg + j];
    float4 v0 = *reinterpret_cast<const float4*>(feat + (size_t)i0 * 128 + c);
    a3.x += v0.x; a3.y += v0.y; a3.z += v0.z; a3.w += v0.w;
  }
  a0.x += a1.x + a2.x + a3.x;
  a0.y += a1.y + a2.y + a3.y;
  a0.z += a1.z + a2.z + a3.z;
  a0.w += a1.w + a2.w + a3.w;
  a0.x += __shfl_xor(a0.x, 32);
  a0.y += __shfl_xor(a0.y, 32);
  a0.z += __shfl_xor(a0.z, 32);
  a0.w += __shfl_xor(a0.w, 32);
  if (half == 0) {
    float invd = 1.0f / fmaxf((float)deg, 1.0f);
    float4 o = {a0.x * invd, a0.y * invd, a0.z * invd, a0.w * invd};
    *reinterpret_cast<float4*>(agg + (size_t)node * 128 + c) = o;
  }
}

// Fused SAGE layer via MFMA: out = relu([agg | root] @ [Wl;Wr] + b)
// 4 waves/block, wave owns 16 rows x 128 cols. acc += Ah*Wh + Ah*Wl + Al*Wh.
template <bool RELU>
__global__ __launch_bounds__(256) void k_gemm_mfma(
    const float* __restrict__ A0, const float* __restrict__ A1,
    const ushort* __restrict__ wh, const ushort* __restrict__ wl_,
    const float* __restrict__ bias, float* __restrict__ out, int M) {
  const int lane = threadIdx.x & 63;
  const int wave = threadIdx.x >> 6;
  const int row = blockIdx.x * 64 + wave * 16;
  f32x4 acc[8] = {};

  for (int s = 0; s < 8; ++s) {
    const float* A = (s < 4) ? A0 : A1;
    const int kb = (s & 3) * 32;
    const float* ap = A + (size_t)(row + (lane & 15)) * 128 + kb + (lane >> 4) * 8;
    float4 av0 = *reinterpret_cast<const float4*>(ap);
    float4 av1 = *reinterpret_cast<const float4*>(ap + 4);
    float av[8] = {av0.x, av0.y, av0.z, av0.w, av1.x, av1.y, av1.z, av1.w};
    short8v ah, al;
#pragma unroll
    for (int j = 0; j < 8; ++j) {
      unsigned short hb = f2bf(av[j]);
      ah[j] = (short)hb;
      al[j] = (short)f2bf(av[j] - bf2f(hb));
    }
    const size_t sbase = (size_t)s * 8 * 64 * 8 + (size_t)lane * 8;
#pragma unroll
    for (int n = 0; n < 8; ++n) {
      short8v bh = *reinterpret_cast<const short8v*>(wh + sbase + (size_t)n * 64 * 8);
      short8v bl = *reinterpret_cast<const short8v*>(wl_ + sbase + (size_t)n * 64 * 8);
      acc[n] = __builtin_amdgcn_mfma_f32_16x16x32_bf16(ah, bh, acc[n], 0, 0, 0);
      acc[n] = __builtin_amdgcn_mfma_f32_16x16x32_bf16(ah, bl, acc[n], 0, 0, 0);
      acc[n] = __builtin_amdgcn_mfma_f32_16x16x32_bf16(al, bh, acc[n], 0, 0, 0);
    }
  }

  const int r0 = row + (lane >> 4) * 4;
  const int col0 = lane & 15;
#pragma unroll
  for (int n = 0; n < 8; ++n) {
    int col = n * 16 + col0;
    float bv = bias[col];
#pragma unroll
    for (int r = 0; r < 4; ++r) {
      float v = acc[n][r] + bv;
      if (RELU) v = fmaxf(v, 0.f);
      out[(size_t)(r0 + r) * 128 + col] = v;
    }
  }
}

// Output projection via MFMA: out = h @ Wout + bout. K=128 (s=0..3), 4 n-tiles.
__global__ __launch_bounds__(256) void k_out_mfma(
    const float* __restrict__ h, const ushort* __restrict__ wh,
    const ushort* __restrict__ wl_, const float* __restrict__ bias,
    float* __restrict__ out, int M) {
  const int lane = threadIdx.x & 63;
  const int wave = threadIdx.x >> 6;
  const int row = blockIdx.x * 64 + wave * 16;
  f32x4 acc[4] = {};

  for (int s = 0; s < 4; ++s) {
    const int kb = s * 32;
    const float* ap = h + (size_t)(row + (lane & 15)) * 128 + kb + (lane >> 4) * 8;
    float4 av0 = *reinterpret_cast<const float4*>(ap);
    float4 av1 = *reinterpret_cast<const float4*>(ap + 4);
    float av[8] = {av0.x, av0.y, av0.z, av0.w, av1.x, av1.y, av1.z, av1.w};
    short8v ah, al;
#pragma unroll
    for (int j = 0; j < 8; ++j) {
      unsigned short hb = f2bf(av[j]);
      ah[j] = (short)hb;
      al[j] = (short)f2bf(av[j] - bf2f(hb));
    }
    const size_t sbase = (size_t)s * 4 * 64 * 8 + (size_t)lane * 8;
#pragma unroll
    for (int n = 0; n < 4; ++n) {
      short8v bh = *reinterpret_cast<const short8v*>(wh + sbase + (size_t)n * 64 * 8);
      short8v bl = *reinterpret_cast<const short8v*>(wl_ + sbase + (size_t)n * 64 * 8);
      acc[n] = __builtin_amdgcn_mfma_f32_16x16x32_bf16(ah, bh, acc[n], 0, 0, 0);
      acc[n] = __builtin_amdgcn_mfma_f32_16x16x32_bf16(ah, bl, acc[n], 0, 0, 0);
      acc[n] = __builtin_amdgcn_mfma_f32_16x16x32_bf16(al, bh, acc[n], 0, 0, 0);
    }
  }

  const int r0 = row + (lane >> 4) * 4;
  const int col0 = lane & 15;
#pragma unroll
  for (int n = 0; n < 4; ++n) {
    int col = n * 16 + col0;
    float bv = bias[col];
#pragma unroll
    for (int r = 0; r < 4; ++r) {
      out[(size_t)(r0 + r) * 64 + col] = acc[n][r] + bv;
    }
  }
}

extern "C" void kernel_launch(void* const* d_in, const int* in_sizes, int n_in,
                              void* d_out, int out_size, void* d_ws, size_t ws_size,
                              hipStream_t stream) {
  const float* x    = (const float*)d_in[0];
  const int*   ei   = (const int*)d_in[1];
  const float* W1l  = (const float*)d_in[2];
  const float* W1r  = (const float*)d_in[3];
  const float* b1   = (const float*)d_in[4];
  const float* W2l  = (const float*)d_in[5];
  const float* W2r  = (const float*)d_in[6];
  const float* b2   = (const float*)d_in[7];
  const float* Wout = (const float*)d_in[8];
  const float* bout = (const float*)d_in[9];
  float* out = (float*)d_out;

  const int N = in_sizes[0] / 128;
  const int E = in_sizes[1] / 2;
  const int* src = ei;
  const int* dst = ei + E;

  // Workspace layout byte-identical to round 2 (proven fit).
  auto align = [](size_t b) { return (b + 255) & ~(size_t)255; };
  char* p = (char*)d_ws;
  int* cnt     = (int*)p;   p += align((size_t)N * 4);
  int* rowptr  = (int*)p;   p += align((size_t)(N + 1) * 4);
  int* cursor  = (int*)p;   p += align((size_t)N * 4);
  int* csr_src = (int*)p;   p += align((size_t)E * 4);
  float* bufA  = (float*)p; p += (size_t)N * 128 * 4;
  float* bufB  = (float*)p;
  // Scan scratch in bufA head (dead until k_agg).
  int* blockSums = (int*)bufA;
  int* blockOff  = blockSums + 64;
  // Weight packs: w1 in cnt region (dead after escan), w2 in cursor region
  // (dead after fill). 131072 B each <= 160000 B region. Wout pack (32 KB)
  // overwrites w1h (cnt region) AFTER gemm1 has consumed it.
  ushort* w1h = (ushort*)cnt;
  ushort* w1l = w1h + 8 * 8 * 64 * 8;      // +64KB
  ushort* w2h = (ushort*)cursor;
  ushort* w2l = w2h + 8 * 8 * 64 * 8;
  ushort* woh = (ushort*)cnt;              // reuse after gemm1
  ushort* wol = woh + 4 * 4 * 64 * 8;      // +16KB

  hipMemsetAsync(cnt, 0, (size_t)N * 4, stream);

  const int nb = (N + 1023) / 1024;  // 40
  const int gemmBlocks = (N + 63) / 64;
  const int aggBlocks = (N + 3) / 4;

  // CSR build
  k_hist<<<(E + 255) / 256, 256, 0, stream>>>(dst, cnt, E);
  k_bsum<<<nb, 1024, 0, stream>>>(cnt, blockSums, N);
  k_bscan<<<1, 64, 0, stream>>>(blockSums, blockOff, rowptr, nb, N);
  k_escan<<<nb, 1024, 0, stream>>>(cnt, blockOff, rowptr, cursor, N);
  k_fill<<<(E + 255) / 256, 256, 0, stream>>>(src, dst, cursor, csr_src, E);

  // Pack W1+W2 (cnt/cursor dead now)
  k_packw12<<<32, 256, 0, stream>>>(W1l, W1r, W2l, W2r, w1h, w1l, w2h, w2l);

  // Layer 1
  k_agg<<<aggBlocks, 256, 0, stream>>>(x, rowptr, csr_src, bufA, N);
  k_gemm_mfma<true><<<gemmBlocks, 256, 0, stream>>>(bufA, x, w1h, w1l, b1, bufB, N);

  // Pack Wout into w1's slot (dead after gemm1)
  k_packwout<<<4, 256, 0, stream>>>(Wout, woh, wol);

  // Layer 2
  k_agg<<<aggBlocks, 256, 0, stream>>>(bufB, rowptr, csr_src, bufA, N);
  k_gemm_mfma<true><<<gemmBlocks, 256, 0, stream>>>(bufA, bufB, w2h, w2l, b2, bufB, N);

  // Output projection (MFMA)
  k_out_mfma<<<gemmBlocks, 256, 0, stream>>>(bufB, woh, wol, bout, out, N);
}

// Round 11
// 204.675 us; speedup vs baseline: 1.7118x; 1.0775x over previous
//
#include <hip/hip_runtime.h>

// GraphSAGE: 2x SAGEConv(mean) + ReLU, then linear out.
// N=40000, E=640000, IN=H=128, OUT=64.
// Round 11: fp16 gather tables (10 mantissa bits: 8x finer than bf16 ->
// gather error ~0.011 vs bf16's measured 0.086; threshold 0.054).
// h1 stored as fp16 hi+lo (=f32-class) so the layer-2 ROOT path stays exact;
// gather2 reads hi only. agg accumulate f32; MFMA hi/lo bf16 GEMMs unchanged.
// Workspace layout byte-identical to r2/r10 (proven 44.0 MB).

typedef __attribute__((ext_vector_type(8))) short short8v;   // 8 bf16
typedef __attribute__((ext_vector_type(4))) float f32x4;
typedef __attribute__((ext_vector_type(4))) _Float16 half4v; // 8B
typedef __attribute__((ext_vector_type(8))) _Float16 half8v; // 16B

static __device__ __forceinline__ unsigned short f2bf(float f) {
  unsigned u = __float_as_uint(f);
  u += 0x7fffu + ((u >> 16) & 1u);   // RNE
  return (unsigned short)(u >> 16);
}
static __device__ __forceinline__ float bf2f(unsigned short h) {
  return __uint_as_float(((unsigned)h) << 16);
}

__global__ __launch_bounds__(256) void k_hist(const int* __restrict__ dst,
                                              int* __restrict__ cnt, int E) {
  int e = blockIdx.x * 256 + threadIdx.x;
  if (e < E) atomicAdd(&cnt[dst[e]], 1);
}

__global__ __launch_bounds__(1024) void k_bsum(const int* __restrict__ cnt,
                                               int* __restrict__ blockSums, int N) {
  __shared__ int ws[16];
  int i = blockIdx.x * 1024 + threadIdx.x;
  int v = (i < N) ? cnt[i] : 0;
#pragma unroll
  for (int d = 32; d > 0; d >>= 1) v += __shfl_xor(v, d, 64);
  if ((threadIdx.x & 63) == 0) ws[threadIdx.x >> 6] = v;
  __syncthreads();
  if (threadIdx.x == 0) {
    int s = 0;
#pragma unroll
    for (int w = 0; w < 16; ++w) s += ws[w];
    blockSums[blockIdx.x] = s;
  }
}

__global__ __launch_bounds__(64) void k_bscan(const int* __restrict__ blockSums,
                                              int* __restrict__ blockOff,
                                              int* __restrict__ rowptr, int nb, int N) {
  if (threadIdx.x == 0) {
    int run = 0;
    for (int i = 0; i < nb; ++i) {
      blockOff[i] = run;
      run += blockSums[i];
    }
    rowptr[N] = run;
  }
}

__global__ __launch_bounds__(1024) void k_escan(const int* __restrict__ cnt,
                                                const int* __restrict__ blockOff,
                                                int* __restrict__ rowptr,
                                                int* __restrict__ cursor, int N) {
  __shared__ int warpSums[16];
  const int tid = threadIdx.x;
  const int lane = tid & 63, wid = tid >> 6;
  int i = blockIdx.x * 1024 + tid;
  int v = (i < N) ? cnt[i] : 0;
  int s = v;
#pragma unroll
  for (int d = 1; d < 64; d <<= 1) {
    int t = __shfl_up(s, d, 64);
    if (lane >= d) s += t;
  }
  if (lane == 63) warpSums[wid] = s;
  __syncthreads();
  if (tid < 16) {
    int w = warpSums[tid];
#pragma unroll
    for (int d = 1; d < 16; d <<= 1) {
      int t = __shfl_up(w, d, 16);
      if (tid >= d) w += t;
    }
    warpSums[tid] = w;
  }
  __syncthreads();
  int ex = blockOff[blockIdx.x] + (wid ? warpSums[wid - 1] : 0) + s - v;
  if (i < N) {
    rowptr[i] = ex;
    cursor[i] = ex;
  }
}

__global__ __launch_bounds__(256) void k_fill(const int* __restrict__ src,
                                              const int* __restrict__ dst,
                                              int* __restrict__ cursor,
                                              int* __restrict__ csr_src, int E) {
  int e = blockIdx.x * 256 + threadIdx.x;
  if (e < E) {
    int pos = atomicAdd(&cursor[dst[e]], 1);
    csr_src[pos] = src[e];
  }
}

// f32 -> fp16 table conversion (4 elems/thread).
__global__ __launch_bounds__(256) void k_convh(const float* __restrict__ in,
                                               _Float16* __restrict__ outh, int n4) {
  int i = blockIdx.x * 256 + threadIdx.x;
  if (i >= n4) return;
  float4 v = reinterpret_cast<const float4*>(in)[i];
  half4v o = {(_Float16)v.x, (_Float16)v.y, (_Float16)v.z, (_Float16)v.w};
  reinterpret_cast<half4v*>(outh)[i] = o;
}

// Pack W1=[W1l;W1r] and W2=[W2l;W2r] (256x128 each) into MFMA B-fragment
// order, bf16 hi/lo. 8192 threads (t<4096: W1, else W2).
__global__ __launch_bounds__(256) void k_packw12(
    const float* __restrict__ W1l, const float* __restrict__ W1r,
    const float* __restrict__ W2l, const float* __restrict__ W2r,
    ushort* __restrict__ w1h, ushort* __restrict__ w1lo,
    ushort* __restrict__ w2h, ushort* __restrict__ w2lo) {
  int t = blockIdx.x * 256 + threadIdx.x;
  if (t >= 8192) return;
  const bool is2 = t >= 4096;
  int u = t & 4095;
  const float* Wl = is2 ? W2l : W1l;
  const float* Wr = is2 ? W2r : W1r;
  ushort* wh = is2 ? w2h : w1h;
  ushort* wlo = is2 ? w2lo : w1lo;
  int l = u & 63;
  int n = (u >> 6) & 7;
  int s = u >> 9;
  int col = n * 16 + (l & 15);
  int kb = s * 32 + ((l >> 4) * 8);
  size_t base = ((size_t)(s * 8 + n) * 64 + l) * 8;
#pragma unroll
  for (int j = 0; j < 8; ++j) {
    int k = kb + j;
    float w = (k < 128) ? Wl[(size_t)k * 128 + col] : Wr[(size_t)(k - 128) * 128 + col];
    unsigned short hb = f2bf(w);
    wh[base + j] = hb;
    wlo[base + j] = f2bf(w - bf2f(hb));
  }
}

// Pack Wout (128x64): s=0..3, n=0..3. 1024 threads.
__global__ __launch_bounds__(256) void k_packwout(const float* __restrict__ Wout,
                                                  ushort* __restrict__ wh,
                                                  ushort* __restrict__ wlo) {
  int t = blockIdx.x * 256 + threadIdx.x;
  if (t >= 1024) return;
  int l = t & 63;
  int n = (t >> 6) & 3;
  int s = t >> 8;
  int col = n * 16 + (l & 15);
  int kb = s * 32 + ((l >> 4) * 8);
  size_t base = ((size_t)(s * 4 + n) * 64 + l) * 8;
#pragma unroll
  for (int j = 0; j < 8; ++j) {
    float w = Wout[(size_t)(kb + j) * 64 + col];
    unsigned short hb = f2bf(w);
    wh[base + j] = hb;
    wlo[base + j] = f2bf(w - bf2f(hb));
  }
}

// One wave per node: mean of fp16 neighbor rows (128 feats), f32 accumulate.
// 32-lane halves, half4 (8B)/lane, 8 rows in flight; 4/2/1 tail cascade.
__global__ __launch_bounds__(256) void k_agg(const _Float16* __restrict__ feat,
                                             const int* __restrict__ rowptr,
                                             const int* __restrict__ csr_src,
                                             float* __restrict__ agg, int N) {
  int node = (blockIdx.x * 256 + threadIdx.x) >> 6;
  if (node >= N) return;
  const int lane = threadIdx.x & 63;
  const int half = lane >> 5;
  const int c = (lane & 31) * 4;
  const int beg = rowptr[node];
  const int deg = rowptr[node + 1] - beg;
  float4 a0 = {0.f, 0.f, 0.f, 0.f}, a1 = a0, a2 = a0, a3 = a0;
  int j = 0;
  for (; j + 7 < deg; j += 8) {
    int i0 = csr_src[beg + j + 0 + half];
    int i1 = csr_src[beg + j + 2 + half];
    int i2 = csr_src[beg + j + 4 + half];
    int i3 = csr_src[beg + j + 6 + half];
    half4v v0 = *reinterpret_cast<const half4v*>(feat + (size_t)i0 * 128 + c);
    half4v v1 = *reinterpret_cast<const half4v*>(feat + (size_t)i1 * 128 + c);
    half4v v2 = *reinterpret_cast<const half4v*>(feat + (size_t)i2 * 128 + c);
    half4v v3 = *reinterpret_cast<const half4v*>(feat + (size_t)i3 * 128 + c);
    a0.x += (float)v0[0]; a0.y += (float)v0[1]; a0.z += (float)v0[2]; a0.w += (float)v0[3];
    a1.x += (float)v1[0]; a1.y += (float)v1[1]; a1.z += (float)v1[2]; a1.w += (float)v1[3];
    a2.x += (float)v2[0]; a2.y += (float)v2[1]; a2.z += (float)v2[2]; a2.w += (float)v2[3];
    a3.x += (float)v3[0]; a3.y += (float)v3[1]; a3.z += (float)v3[2]; a3.w += (float)v3[3];
  }
  if (j + 3 < deg) {
    int i0 = csr_src[beg + j + 0 + half];
    int i1 = csr_src[beg + j + 2 + half];
    half4v v0 = *reinterpret_cast<const half4v*>(feat + (size_t)i0 * 128 + c);
    half4v v1 = *reinterpret_cast<const half4v*>(feat + (size_t)i1 * 128 + c);
    a0.x += (float)v0[0]; a0.y += (float)v0[1]; a0.z += (float)v0[2]; a0.w += (float)v0[3];
    a1.x += (float)v1[0]; a1.y += (float)v1[1]; a1.z += (float)v1[2]; a1.w += (float)v1[3];
    j += 4;
  }
  if (j + 1 < deg) {
    int i0 = csr_src[beg + j + half];
    half4v v0 = *reinterpret_cast<const half4v*>(feat + (size_t)i0 * 128 + c);
    a2.x += (float)v0[0]; a2.y += (float)v0[1]; a2.z += (float)v0[2]; a2.w += (float)v0[3];
    j += 2;
  }
  if (j < deg && half == 0) {
    int i0 = csr_src[beg + j];
    half4v v0 = *reinterpret_cast<const half4v*>(feat + (size_t)i0 * 128 + c);
    a3.x += (float)v0[0]; a3.y += (float)v0[1]; a3.z += (float)v0[2]; a3.w += (float)v0[3];
  }
  a0.x += a1.x + a2.x + a3.x;
  a0.y += a1.y + a2.y + a3.y;
  a0.z += a1.z + a2.z + a3.z;
  a0.w += a1.w + a2.w + a3.w;
  a0.x += __shfl_xor(a0.x, 32);
  a0.y += __shfl_xor(a0.y, 32);
  a0.z += __shfl_xor(a0.z, 32);
  a0.w += __shfl_xor(a0.w, 32);
  if (half == 0) {
    float invd = 1.0f / fmaxf((float)deg, 1.0f);
    float4 o = {a0.x * invd, a0.y * invd, a0.z * invd, a0.w * invd};
    *reinterpret_cast<float4*>(agg + (size_t)node * 128 + c) = o;
  }
}

// Fused SAGE layer via MFMA: out = relu([agg | root] @ [Wl;Wr] + b)
// ROOTM: 0 = f32 root, 1 = fp16 hi+lo root (f32-class reconstruct)
// OUTM:  0 = f32 out,  1 = fp16 hi+lo out
// 4 waves/block, wave = 16 rows x 128 cols. acc += Ah*Wh + Ah*Wl + Al*Wh.
template <bool RELU, int ROOTM, int OUTM>
__global__ __launch_bounds__(256) void k_gemm_mfma(
    const float* __restrict__ A0, const float* __restrict__ rootf,
    const _Float16* __restrict__ rooth, const _Float16* __restrict__ rootl,
    const ushort* __restrict__ wh, const ushort* __restrict__ wl_,
    const float* __restrict__ bias, float* __restrict__ outf,
    _Float16* __restrict__ outh, _Float16* __restrict__ outl, int M) {
  const int lane = threadIdx.x & 63;
  const int wave = threadIdx.x >> 6;
  const int row = blockIdx.x * 64 + wave * 16;
  f32x4 acc[8] = {};

  for (int s = 0; s < 8; ++s) {
    const int kb = (s & 3) * 32;
    const size_t aoff = (size_t)(row + (lane & 15)) * 128 + kb + (lane >> 4) * 8;
    float av[8];
    if (s < 4) {
      float4 av0 = *reinterpret_cast<const float4*>(A0 + aoff);
      float4 av1 = *reinterpret_cast<const float4*>(A0 + aoff + 4);
      av[0] = av0.x; av[1] = av0.y; av[2] = av0.z; av[3] = av0.w;
      av[4] = av1.x; av[5] = av1.y; av[6] = av1.z; av[7] = av1.w;
    } else if (ROOTM == 0) {
      float4 av0 = *reinterpret_cast<const float4*>(rootf + aoff);
      float4 av1 = *reinterpret_cast<const float4*>(rootf + aoff + 4);
      av[0] = av0.x; av[1] = av0.y; av[2] = av0.z; av[3] = av0.w;
      av[4] = av1.x; av[5] = av1.y; av[6] = av1.z; av[7] = av1.w;
    } else {
      half8v hv = *reinterpret_cast<const half8v*>(rooth + aoff);
      half8v lv = *reinterpret_cast<const half8v*>(rootl + aoff);
#pragma unroll
      for (int j = 0; j < 8; ++j) av[j] = (float)hv[j] + (float)lv[j];
    }
    short8v ah, al;
#pragma unroll
    for (int j = 0; j < 8; ++j) {
      unsigned short hb = f2bf(av[j]);
      ah[j] = (short)hb;
      al[j] = (short)f2bf(av[j] - bf2f(hb));
    }
    const size_t sbase = (size_t)s * 8 * 64 * 8 + (size_t)lane * 8;
#pragma unroll
    for (int n = 0; n < 8; ++n) {
      short8v bh = *reinterpret_cast<const short8v*>(wh + sbase + (size_t)n * 64 * 8);
      short8v bl = *reinterpret_cast<const short8v*>(wl_ + sbase + (size_t)n * 64 * 8);
      acc[n] = __builtin_amdgcn_mfma_f32_16x16x32_bf16(ah, bh, acc[n], 0, 0, 0);
      acc[n] = __builtin_amdgcn_mfma_f32_16x16x32_bf16(ah, bl, acc[n], 0, 0, 0);
      acc[n] = __builtin_amdgcn_mfma_f32_16x16x32_bf16(al, bh, acc[n], 0, 0, 0);
    }
  }

  const int r0 = row + (lane >> 4) * 4;
  const int col0 = lane & 15;
#pragma unroll
  for (int n = 0; n < 8; ++n) {
    int col = n * 16 + col0;
    float bv = bias[col];
#pragma unroll
    for (int r = 0; r < 4; ++r) {
      float v = acc[n][r] + bv;
      if (RELU) v = fmaxf(v, 0.f);
      if (OUTM == 0) {
        outf[(size_t)(r0 + r) * 128 + col] = v;
      } else {
        _Float16 hi = (_Float16)v;
        outh[(size_t)(r0 + r) * 128 + col] = hi;
        outl[(size_t)(r0 + r) * 128 + col] = (_Float16)(v - (float)hi);
      }
    }
  }
}

// Output projection via MFMA: out = h @ Wout + bout. K=128 (s=0..3), 4 n-tiles.
__global__ __launch_bounds__(256) void k_out_mfma(
    const float* __restrict__ h, const ushort* __restrict__ wh,
    const ushort* __restrict__ wl_, const float* __restrict__ bias,
    float* __restrict__ out, int M) {
  const int lane = threadIdx.x & 63;
  const int wave = threadIdx.x >> 6;
  const int row = blockIdx.x * 64 + wave * 16;
  f32x4 acc[4] = {};

  for (int s = 0; s < 4; ++s) {
    const int kb = s * 32;
    const float* ap = h + (size_t)(row + (lane & 15)) * 128 + kb + (lane >> 4) * 8;
    float4 av0 = *reinterpret_cast<const float4*>(ap);
    float4 av1 = *reinterpret_cast<const float4*>(ap + 4);
    float av[8] = {av0.x, av0.y, av0.z, av0.w, av1.x, av1.y, av1.z, av1.w};
    short8v ah, al;
#pragma unroll
    for (int j = 0; j < 8; ++j) {
      unsigned short hb = f2bf(av[j]);
      ah[j] = (short)hb;
      al[j] = (short)f2bf(av[j] - bf2f(hb));
    }
    const size_t sbase = (size_t)s * 4 * 64 * 8 + (size_t)lane * 8;
#pragma unroll
    for (int n = 0; n < 4; ++n) {
      short8v bh = *reinterpret_cast<const short8v*>(wh + sbase + (size_t)n * 64 * 8);
      short8v bl = *reinterpret_cast<const short8v*>(wl_ + sbase + (size_t)n * 64 * 8);
      acc[n] = __builtin_amdgcn_mfma_f32_16x16x32_bf16(ah, bh, acc[n], 0, 0, 0);
      acc[n] = __builtin_amdgcn_mfma_f32_16x16x32_bf16(ah, bl, acc[n], 0, 0, 0);
      acc[n] = __builtin_amdgcn_mfma_f32_16x16x32_bf16(al, bh, acc[n], 0, 0, 0);
    }
  }

  const int r0 = row + (lane >> 4) * 4;
  const int col0 = lane & 15;
#pragma unroll
  for (int n = 0; n < 4; ++n) {
    int col = n * 16 + col0;
    float bv = bias[col];
#pragma unroll
    for (int r = 0; r < 4; ++r) {
      out[(size_t)(r0 + r) * 64 + col] = acc[n][r] + bv;
    }
  }
}

extern "C" void kernel_launch(void* const* d_in, const int* in_sizes, int n_in,
                              void* d_out, int out_size, void* d_ws, size_t ws_size,
                              hipStream_t stream) {
  const float* x    = (const float*)d_in[0];
  const int*   ei   = (const int*)d_in[1];
  const float* W1l  = (const float*)d_in[2];
  const float* W1r  = (const float*)d_in[3];
  const float* b1   = (const float*)d_in[4];
  const float* W2l  = (const float*)d_in[5];
  const float* W2r  = (const float*)d_in[6];
  const float* b2   = (const float*)d_in[7];
  const float* Wout = (const float*)d_in[8];
  const float* bout = (const float*)d_in[9];
  float* out = (float*)d_out;

  const int N = in_sizes[0] / 128;
  const int E = in_sizes[1] / 2;
  const int* src = ei;
  const int* dst = ei + E;

  // Workspace layout byte-identical to round 2 (proven fit).
  auto align = [](size_t b) { return (b + 255) & ~(size_t)255; };
  char* p = (char*)d_ws;
  int* cnt     = (int*)p;   p += align((size_t)N * 4);
  int* rowptr  = (int*)p;   p += align((size_t)(N + 1) * 4);
  int* cursor  = (int*)p;   p += align((size_t)N * 4);
  int* csr_src = (int*)p;   p += align((size_t)E * 4);
  float* bufA  = (float*)p; p += (size_t)N * 128 * 4;
  float* bufB  = (float*)p;
  // Scan scratch in bufA head (dead until k_agg).
  int* blockSums = (int*)bufA;
  int* blockOff  = blockSums + 64;
  // fp16 tables live inside bufB (20.5MB): xh in [0,10.25MB) until agg1 done;
  // gemm1 then writes h1h over it and h1lo in [10.25,20.5MB).
  _Float16* xh  = (_Float16*)bufB;
  _Float16* h1h = (_Float16*)bufB;
  _Float16* h1l = h1h + (size_t)N * 128;
  float* h2 = bufA;  // gemm2 writes over agg2 (own rows, after reads)
  // Weight packs: w1 in cnt region (dead after escan), w2 in cursor region.
  // Wout pack overwrites w1 region after gemm1 consumed it.
  ushort* w1h = (ushort*)cnt;
  ushort* w1l = w1h + 8 * 8 * 64 * 8;      // +64KB
  ushort* w2h = (ushort*)cursor;
  ushort* w2l = w2h + 8 * 8 * 64 * 8;
  ushort* woh = (ushort*)cnt;
  ushort* wol = woh + 4 * 4 * 64 * 8;      // +16KB

  hipMemsetAsync(cnt, 0, (size_t)N * 4, stream);

  const int nb = (N + 1023) / 1024;  // 40
  const int gemmBlocks = (N + 63) / 64;
  const int aggBlocks = (N + 3) / 4;

  // CSR build
  k_hist<<<(E + 255) / 256, 256, 0, stream>>>(dst, cnt, E);
  k_bsum<<<nb, 1024, 0, stream>>>(cnt, blockSums, N);
  k_bscan<<<1, 64, 0, stream>>>(blockSums, blockOff, rowptr, nb, N);
  k_escan<<<nb, 1024, 0, stream>>>(cnt, blockOff, rowptr, cursor, N);
  k_fill<<<(E + 255) / 256, 256, 0, stream>>>(src, dst, cursor, csr_src, E);

  // Pack W1+W2 (cnt/cursor dead now); fp16 x table
  k_packw12<<<32, 256, 0, stream>>>(W1l, W1r, W2l, W2r, w1h, w1l, w2h, w2l);
  k_convh<<<((N * 32) + 255) / 256, 256, 0, stream>>>(x, xh, N * 32);

  // Layer 1: gather fp16 x -> f32 agg; root = f32 x; out = fp16 hi/lo h1
  k_agg<<<aggBlocks, 256, 0, stream>>>(xh, rowptr, csr_src, bufA, N);
  k_gemm_mfma<true, 0, 1><<<gemmBlocks, 256, 0, stream>>>(
      bufA, x, nullptr, nullptr, w1h, w1l, b1, nullptr, h1h, h1l, N);

  // Pack Wout into w1's slot (dead after gemm1)
  k_packwout<<<4, 256, 0, stream>>>(Wout, woh, wol);

  // Layer 2: gather fp16 h1h -> f32 agg; root = h1h+h1l (f32-class); out f32
  k_agg<<<aggBlocks, 256, 0, stream>>>(h1h, rowptr, csr_src, bufA, N);
  k_gemm_mfma<true, 1, 0><<<gemmBlocks, 256, 0, stream>>>(
      bufA, nullptr, h1h, h1l, w2h, w2l, b2, h2, nullptr, nullptr, N);

  // Output projection (MFMA)
  k_out_mfma<<<gemmBlocks, 256, 0, stream>>>(h2, woh, wol, bout, out, N);
}

// Round 12
// 198.140 us; speedup vs baseline: 1.7683x; 1.0330x over previous
//
#include <hip/hip_runtime.h>

// GraphSAGE: 2x SAGEConv(mean) + ReLU, then linear out.
// N=40000, E=640000, IN=H=128, OUT=64.
// Round 12: r11 + (1) agg v3: 16-lane/row fp16 gather, 16 rows in flight
// (2x MLP bytes; gather is latency-bound), (2) fused gemm2+out via LDS
// (h2 never materializes: -40MB traffic, -1 launch), (3) merged prep kernel.
// Numerics identical to r11 (fp16 gather tables, hi/lo f32-class elsewhere).
// Workspace layout byte-identical to r2/r11 (proven fit; ws is 256MiB anyway).

typedef __attribute__((ext_vector_type(8))) short short8v;   // 8 bf16
typedef __attribute__((ext_vector_type(4))) float f32x4;
typedef __attribute__((ext_vector_type(4))) _Float16 half4v; // 8B
typedef __attribute__((ext_vector_type(8))) _Float16 half8v; // 16B

static __device__ __forceinline__ unsigned short f2bf(float f) {
  unsigned u = __float_as_uint(f);
  u += 0x7fffu + ((u >> 16) & 1u);   // RNE
  return (unsigned short)(u >> 16);
}
static __device__ __forceinline__ float bf2f(unsigned short h) {
  return __uint_as_float(((unsigned)h) << 16);
}

__global__ __launch_bounds__(256) void k_hist(const int* __restrict__ dst,
                                              int* __restrict__ cnt, int E) {
  int e = blockIdx.x * 256 + threadIdx.x;
  if (e < E) atomicAdd(&cnt[dst[e]], 1);
}

__global__ __launch_bounds__(1024) void k_bsum(const int* __restrict__ cnt,
                                               int* __restrict__ blockSums, int N) {
  __shared__ int ws[16];
  int i = blockIdx.x * 1024 + threadIdx.x;
  int v = (i < N) ? cnt[i] : 0;
#pragma unroll
  for (int d = 32; d > 0; d >>= 1) v += __shfl_xor(v, d, 64);
  if ((threadIdx.x & 63) == 0) ws[threadIdx.x >> 6] = v;
  __syncthreads();
  if (threadIdx.x == 0) {
    int s = 0;
#pragma unroll
    for (int w = 0; w < 16; ++w) s += ws[w];
    blockSums[blockIdx.x] = s;
  }
}

__global__ __launch_bounds__(64) void k_bscan(const int* __restrict__ blockSums,
                                              int* __restrict__ blockOff,
                                              int* __restrict__ rowptr, int nb, int N) {
  if (threadIdx.x == 0) {
    int run = 0;
    for (int i = 0; i < nb; ++i) {
      blockOff[i] = run;
      run += blockSums[i];
    }
    rowptr[N] = run;
  }
}

__global__ __launch_bounds__(1024) void k_escan(const int* __restrict__ cnt,
                                                const int* __restrict__ blockOff,
                                                int* __restrict__ rowptr,
                                                int* __restrict__ cursor, int N) {
  __shared__ int warpSums[16];
  const int tid = threadIdx.x;
  const int lane = tid & 63, wid = tid >> 6;
  int i = blockIdx.x * 1024 + tid;
  int v = (i < N) ? cnt[i] : 0;
  int s = v;
#pragma unroll
  for (int d = 1; d < 64; d <<= 1) {
    int t = __shfl_up(s, d, 64);
    if (lane >= d) s += t;
  }
  if (lane == 63) warpSums[wid] = s;
  __syncthreads();
  if (tid < 16) {
    int w = warpSums[tid];
#pragma unroll
    for (int d = 1; d < 16; d <<= 1) {
      int t = __shfl_up(w, d, 16);
      if (tid >= d) w += t;
    }
    warpSums[tid] = w;
  }
  __syncthreads();
  int ex = blockOff[blockIdx.x] + (wid ? warpSums[wid - 1] : 0) + s - v;
  if (i < N) {
    rowptr[i] = ex;
    cursor[i] = ex;
  }
}

__global__ __launch_bounds__(256) void k_fill(const int* __restrict__ src,
                                              const int* __restrict__ dst,
                                              int* __restrict__ cursor,
                                              int* __restrict__ csr_src, int E) {
  int e = blockIdx.x * 256 + threadIdx.x;
  if (e < E) {
    int pos = atomicAdd(&cursor[dst[e]], 1);
    csr_src[pos] = src[e];
  }
}

// Merged prep: t<8192 -> pack W1/W2 fragments (bf16 hi/lo); else fp16 x table.
__global__ __launch_bounds__(256) void k_prep(
    const float* __restrict__ W1l, const float* __restrict__ W1r,
    const float* __restrict__ W2l, const float* __restrict__ W2r,
    ushort* __restrict__ w1h, ushort* __restrict__ w1lo,
    ushort* __restrict__ w2h, ushort* __restrict__ w2lo,
    const float* __restrict__ x, _Float16* __restrict__ xh, int n4) {
  int t = blockIdx.x * 256 + threadIdx.x;
  if (t < 8192) {
    const bool is2 = t >= 4096;
    int u = t & 4095;
    const float* Wl = is2 ? W2l : W1l;
    const float* Wr = is2 ? W2r : W1r;
    ushort* wh = is2 ? w2h : w1h;
    ushort* wlo = is2 ? w2lo : w1lo;
    int l = u & 63;
    int n = (u >> 6) & 7;
    int s = u >> 9;
    int col = n * 16 + (l & 15);
    int kb = s * 32 + ((l >> 4) * 8);
    size_t base = ((size_t)(s * 8 + n) * 64 + l) * 8;
#pragma unroll
    for (int j = 0; j < 8; ++j) {
      int k = kb + j;
      float w = (k < 128) ? Wl[(size_t)k * 128 + col] : Wr[(size_t)(k - 128) * 128 + col];
      unsigned short hb = f2bf(w);
      wh[base + j] = hb;
      wlo[base + j] = f2bf(w - bf2f(hb));
    }
  } else {
    int i = t - 8192;
    if (i >= n4) return;
    float4 v = reinterpret_cast<const float4*>(x)[i];
    half4v o = {(_Float16)v.x, (_Float16)v.y, (_Float16)v.z, (_Float16)v.w};
    reinterpret_cast<half4v*>(xh)[i] = o;
  }
}

// Pack Wout (128x64): s=0..3, n=0..3. 1024 threads.
__global__ __launch_bounds__(256) void k_packwout(const float* __restrict__ Wout,
                                                  ushort* __restrict__ wh,
                                                  ushort* __restrict__ wlo) {
  int t = blockIdx.x * 256 + threadIdx.x;
  if (t >= 1024) return;
  int l = t & 63;
  int n = (t >> 6) & 3;
  int s = t >> 8;
  int col = n * 16 + (l & 15);
  int kb = s * 32 + ((l >> 4) * 8);
  size_t base = ((size_t)(s * 4 + n) * 64 + l) * 8;
#pragma unroll
  for (int j = 0; j < 8; ++j) {
    float w = Wout[(size_t)(kb + j) * 64 + col];
    unsigned short hb = f2bf(w);
    wh[base + j] = hb;
    wlo[base + j] = f2bf(w - bf2f(hb));
  }
}

// One wave per node: mean of fp16 neighbor rows (128 feats), f32 accumulate.
// 16 lanes per row (16B half8v/lane), 4 rows per iter via quarters, 4-deep
// -> 16 rows in flight per wave. Reduction: xor16 + xor32.
__global__ __launch_bounds__(256) void k_agg(const _Float16* __restrict__ feat,
                                             const int* __restrict__ rowptr,
                                             const int* __restrict__ csr_src,
                                             float* __restrict__ agg, int N) {
  int node = (blockIdx.x * 256 + threadIdx.x) >> 6;
  if (node >= N) return;
  const int lane = threadIdx.x & 63;
  const int q = lane >> 4;          // quarter 0..3
  const int c = (lane & 15) * 8;    // feature base (8 fp16 = 16B)
  const int beg = rowptr[node];
  const int deg = rowptr[node + 1] - beg;
  float a0[8] = {}, a1[8] = {}, a2[8] = {}, a3[8] = {};
  for (int j = 0; j < deg; j += 16) {
    int r0 = j + q, r1 = j + 4 + q, r2 = j + 8 + q, r3 = j + 12 + q;
    if (r0 < deg) {
      int i0 = csr_src[beg + r0];
      half8v v = *reinterpret_cast<const half8v*>(feat + (size_t)i0 * 128 + c);
#pragma unroll
      for (int t = 0; t < 8; ++t) a0[t] += (float)v[t];
    }
    if (r1 < deg) {
      int i1 = csr_src[beg + r1];
      half8v v = *reinterpret_cast<const half8v*>(feat + (size_t)i1 * 128 + c);
#pragma unroll
      for (int t = 0; t < 8; ++t) a1[t] += (float)v[t];
    }
    if (r2 < deg) {
      int i2 = csr_src[beg + r2];
      half8v v = *reinterpret_cast<const half8v*>(feat + (size_t)i2 * 128 + c);
#pragma unroll
      for (int t = 0; t < 8; ++t) a2[t] += (float)v[t];
    }
    if (r3 < deg) {
      int i3 = csr_src[beg + r3];
      half8v v = *reinterpret_cast<const half8v*>(feat + (size_t)i3 * 128 + c);
#pragma unroll
      for (int t = 0; t < 8; ++t) a3[t] += (float)v[t];
    }
  }
  float s[8];
#pragma unroll
  for (int t = 0; t < 8; ++t) {
    s[t] = (a0[t] + a1[t]) + (a2[t] + a3[t]);
    s[t] += __shfl_xor(s[t], 16);
    s[t] += __shfl_xor(s[t], 32);
  }
  if (lane < 16) {
    float invd = 1.0f / fmaxf((float)deg, 1.0f);
    float4 o0 = {s[0] * invd, s[1] * invd, s[2] * invd, s[3] * invd};
    float4 o1 = {s[4] * invd, s[5] * invd, s[6] * invd, s[7] * invd};
    *reinterpret_cast<float4*>(agg + (size_t)node * 128 + c) = o0;
    *reinterpret_cast<float4*>(agg + (size_t)node * 128 + c + 4) = o1;
  }
}

// SAGE layer 1 via MFMA: h1 = relu([agg | x] @ W1 + b1), out fp16 hi/lo.
__global__ __launch_bounds__(256) void k_gemm1(
    const float* __restrict__ A0, const float* __restrict__ rootf,
    const ushort* __restrict__ wh, const ushort* __restrict__ wl_,
    const float* __restrict__ bias, _Float16* __restrict__ outh,
    _Float16* __restrict__ outl, int M) {
  const int lane = threadIdx.x & 63;
  const int wave = threadIdx.x >> 6;
  const int row = blockIdx.x * 64 + wave * 16;
  f32x4 acc[8] = {};

  for (int s = 0; s < 8; ++s) {
    const int kb = (s & 3) * 32;
    const size_t aoff = (size_t)(row + (lane & 15)) * 128 + kb + (lane >> 4) * 8;
    const float* ap = (s < 4) ? (A0 + aoff) : (rootf + aoff);
    float4 av0 = *reinterpret_cast<const float4*>(ap);
    float4 av1 = *reinterpret_cast<const float4*>(ap + 4);
    float av[8] = {av0.x, av0.y, av0.z, av0.w, av1.x, av1.y, av1.z, av1.w};
    short8v ah, al;
#pragma unroll
    for (int j = 0; j < 8; ++j) {
      unsigned short hb = f2bf(av[j]);
      ah[j] = (short)hb;
      al[j] = (short)f2bf(av[j] - bf2f(hb));
    }
    const size_t sbase = (size_t)s * 8 * 64 * 8 + (size_t)lane * 8;
#pragma unroll
    for (int n = 0; n < 8; ++n) {
      short8v bh = *reinterpret_cast<const short8v*>(wh + sbase + (size_t)n * 64 * 8);
      short8v bl = *reinterpret_cast<const short8v*>(wl_ + sbase + (size_t)n * 64 * 8);
      acc[n] = __builtin_amdgcn_mfma_f32_16x16x32_bf16(ah, bh, acc[n], 0, 0, 0);
      acc[n] = __builtin_amdgcn_mfma_f32_16x16x32_bf16(ah, bl, acc[n], 0, 0, 0);
      acc[n] = __builtin_amdgcn_mfma_f32_16x16x32_bf16(al, bh, acc[n], 0, 0, 0);
    }
  }

  const int r0 = row + (lane >> 4) * 4;
  const int col0 = lane & 15;
#pragma unroll
  for (int n = 0; n < 8; ++n) {
    int col = n * 16 + col0;
    float bv = bias[col];
#pragma unroll
    for (int r = 0; r < 4; ++r) {
      float v = fmaxf(acc[n][r] + bv, 0.f);
      _Float16 hi = (_Float16)v;
      outh[(size_t)(r0 + r) * 128 + col] = hi;
      outl[(size_t)(r0 + r) * 128 + col] = (_Float16)(v - (float)hi);
    }
  }
}

// Fused layer2 + out-projection: h2 = relu([agg|h1]@W2+b2) staged in LDS,
// then out = h2 @ Wout + bout. h2 never touches global.
__global__ __launch_bounds__(256) void k_gemm2_out(
    const float* __restrict__ A0, const _Float16* __restrict__ rooth,
    const _Float16* __restrict__ rootl, const ushort* __restrict__ w2h,
    const ushort* __restrict__ w2l, const float* __restrict__ b2,
    const ushort* __restrict__ woh, const ushort* __restrict__ wol,
    const float* __restrict__ bout, float* __restrict__ out, int M) {
  __shared__ float H[64][132];
  const int lane = threadIdx.x & 63;
  const int wave = threadIdx.x >> 6;
  const int row = blockIdx.x * 64 + wave * 16;
  f32x4 acc[8] = {};

  // Phase 1: h2 tile
  for (int s = 0; s < 8; ++s) {
    const int kb = (s & 3) * 32;
    const size_t aoff = (size_t)(row + (lane & 15)) * 128 + kb + (lane >> 4) * 8;
    float av[8];
    if (s < 4) {
      float4 av0 = *reinterpret_cast<const float4*>(A0 + aoff);
      float4 av1 = *reinterpret_cast<const float4*>(A0 + aoff + 4);
      av[0] = av0.x; av[1] = av0.y; av[2] = av0.z; av[3] = av0.w;
      av[4] = av1.x; av[5] = av1.y; av[6] = av1.z; av[7] = av1.w;
    } else {
      half8v hv = *reinterpret_cast<const half8v*>(rooth + aoff);
      half8v lv = *reinterpret_cast<const half8v*>(rootl + aoff);
#pragma unroll
      for (int j = 0; j < 8; ++j) av[j] = (float)hv[j] + (float)lv[j];
    }
    short8v ah, al;
#pragma unroll
    for (int j = 0; j < 8; ++j) {
      unsigned short hb = f2bf(av[j]);
      ah[j] = (short)hb;
      al[j] = (short)f2bf(av[j] - bf2f(hb));
    }
    const size_t sbase = (size_t)s * 8 * 64 * 8 + (size_t)lane * 8;
#pragma unroll
    for (int n = 0; n < 8; ++n) {
      short8v bh = *reinterpret_cast<const short8v*>(w2h + sbase + (size_t)n * 64 * 8);
      short8v bl = *reinterpret_cast<const short8v*>(w2l + sbase + (size_t)n * 64 * 8);
      acc[n] = __builtin_amdgcn_mfma_f32_16x16x32_bf16(ah, bh, acc[n], 0, 0, 0);
      acc[n] = __builtin_amdgcn_mfma_f32_16x16x32_bf16(ah, bl, acc[n], 0, 0, 0);
      acc[n] = __builtin_amdgcn_mfma_f32_16x16x32_bf16(al, bh, acc[n], 0, 0, 0);
    }
  }

  // h2 -> LDS (relu + bias)
  const int r0loc = wave * 16 + (lane >> 4) * 4;
  const int col0 = lane & 15;
#pragma unroll
  for (int n = 0; n < 8; ++n) {
    int col = n * 16 + col0;
    float bv = b2[col];
#pragma unroll
    for (int r = 0; r < 4; ++r) {
      H[r0loc + r][col] = fmaxf(acc[n][r] + bv, 0.f);
    }
  }
  __syncthreads();

  // Phase 2: out = H @ Wout + bout (each wave consumes its own 16 rows)
  f32x4 acc2[4] = {};
  for (int s = 0; s < 4; ++s) {
    const float* hp = &H[wave * 16 + (lane & 15)][s * 32 + (lane >> 4) * 8];
    float av[8];
#pragma unroll
    for (int j = 0; j < 8; ++j) av[j] = hp[j];
    short8v ah, al;
#pragma unroll
    for (int j = 0; j < 8; ++j) {
      unsigned short hb = f2bf(av[j]);
      ah[j] = (short)hb;
      al[j] = (short)f2bf(av[j] - bf2f(hb));
    }
    const size_t sbase = (size_t)s * 4 * 64 * 8 + (size_t)lane * 8;
#pragma unroll
    for (int n = 0; n < 4; ++n) {
      short8v bh = *reinterpret_cast<const short8v*>(woh + sbase + (size_t)n * 64 * 8);
      short8v bl = *reinterpret_cast<const short8v*>(wol + sbase + (size_t)n * 64 * 8);
      acc2[n] = __builtin_amdgcn_mfma_f32_16x16x32_bf16(ah, bh, acc2[n], 0, 0, 0);
      acc2[n] = __builtin_amdgcn_mfma_f32_16x16x32_bf16(ah, bl, acc2[n], 0, 0, 0);
      acc2[n] = __builtin_amdgcn_mfma_f32_16x16x32_bf16(al, bh, acc2[n], 0, 0, 0);
    }
  }

  const int r0 = row + (lane >> 4) * 4;
#pragma unroll
  for (int n = 0; n < 4; ++n) {
    int col = n * 16 + col0;
    float bv = bout[col];
#pragma unroll
    for (int r = 0; r < 4; ++r) {
      out[(size_t)(r0 + r) * 64 + col] = acc2[n][r] + bv;
    }
  }
}

extern "C" void kernel_launch(void* const* d_in, const int* in_sizes, int n_in,
                              void* d_out, int out_size, void* d_ws, size_t ws_size,
                              hipStream_t stream) {
  const float* x    = (const float*)d_in[0];
  const int*   ei   = (const int*)d_in[1];
  const float* W1l  = (const float*)d_in[2];
  const float* W1r  = (const float*)d_in[3];
  const float* b1   = (const float*)d_in[4];
  const float* W2l  = (const float*)d_in[5];
  const float* W2r  = (const float*)d_in[6];
  const float* b2   = (const float*)d_in[7];
  const float* Wout = (const float*)d_in[8];
  const float* bout = (const float*)d_in[9];
  float* out = (float*)d_out;

  const int N = in_sizes[0] / 128;
  const int E = in_sizes[1] / 2;
  const int* src = ei;
  const int* dst = ei + E;

  // Workspace layout byte-identical to round 2 (proven fit).
  auto align = [](size_t b) { return (b + 255) & ~(size_t)255; };
  char* p = (char*)d_ws;
  int* cnt     = (int*)p;   p += align((size_t)N * 4);
  int* rowptr  = (int*)p;   p += align((size_t)(N + 1) * 4);
  int* cursor  = (int*)p;   p += align((size_t)N * 4);
  int* csr_src = (int*)p;   p += align((size_t)E * 4);
  float* bufA  = (float*)p; p += (size_t)N * 128 * 4;
  float* bufB  = (float*)p;
  // Scan scratch in bufA head (dead until k_agg).
  int* blockSums = (int*)bufA;
  int* blockOff  = blockSums + 64;
  // fp16 tables inside bufB: xh until agg1 done; then h1h over it, h1l after.
  _Float16* xh  = (_Float16*)bufB;
  _Float16* h1h = (_Float16*)bufB;
  _Float16* h1l = h1h + (size_t)N * 128;
  // Weight packs: w1 in cnt region (dead after escan), w2 in cursor region.
  // Wout pack overwrites w1 region after gemm1 consumed it.
  ushort* w1h = (ushort*)cnt;
  ushort* w1l = w1h + 8 * 8 * 64 * 8;      // +64KB
  ushort* w2h = (ushort*)cursor;
  ushort* w2l = w2h + 8 * 8 * 64 * 8;
  ushort* woh = (ushort*)cnt;
  ushort* wol = woh + 4 * 4 * 64 * 8;      // +16KB

  hipMemsetAsync(cnt, 0, (size_t)N * 4, stream);

  const int nb = (N + 1023) / 1024;  // 40
  const int gemmBlocks = (N + 63) / 64;
  const int aggBlocks = (N + 3) / 4;
  const int prepBlocks = (8192 + N * 32 + 255) / 256;

  // CSR build
  k_hist<<<(E + 255) / 256, 256, 0, stream>>>(dst, cnt, E);
  k_bsum<<<nb, 1024, 0, stream>>>(cnt, blockSums, N);
  k_bscan<<<1, 64, 0, stream>>>(blockSums, blockOff, rowptr, nb, N);
  k_escan<<<nb, 1024, 0, stream>>>(cnt, blockOff, rowptr, cursor, N);
  k_fill<<<(E + 255) / 256, 256, 0, stream>>>(src, dst, cursor, csr_src, E);

  // Prep: W1/W2 fragment packs + fp16 x table (cnt/cursor dead now)
  k_prep<<<prepBlocks, 256, 0, stream>>>(W1l, W1r, W2l, W2r,
                                         w1h, w1l, w2h, w2l, x, xh, N * 32);

  // Layer 1: gather fp16 x -> f32 agg; root = f32 x; out = fp16 hi/lo h1
  k_agg<<<aggBlocks, 256, 0, stream>>>(xh, rowptr, csr_src, bufA, N);
  k_gemm1<<<gemmBlocks, 256, 0, stream>>>(bufA, x, w1h, w1l, b1, h1h, h1l, N);

  // Pack Wout into w1's slot (dead after gemm1)
  k_packwout<<<4, 256, 0, stream>>>(Wout, woh, wol);

  // Layer 2 + output projection fused (h2 stays in LDS)
  k_agg<<<aggBlocks, 256, 0, stream>>>(h1h, rowptr, csr_src, bufA, N);
  k_gemm2_out<<<gemmBlocks, 256, 0, stream>>>(bufA, h1h, h1l, w2h, w2l, b2,
                                              woh, wol, bout, out, N);
}